// Round 1
// baseline (24824.240 us; speedup 1.0000x reference)
//
#include <hip/hip_runtime.h>
#include <math.h>

// ---------------- problem constants ----------------
namespace {
constexpr int CB = 8, CS = 256, CSD = 768, CL = 12, CNH = 12, CDH = 64, CFF = 3072;
constexpr int CK = 5, CD = 200, CHC = 4, CDPH = 50, CNNT = 4, CNET = 38;
constexpr int CNN = 200, CN = 1600, CE = 50000, CEN = 51600, CIE = 200;

// workspace offsets (floats)
constexpr long long OQ    = 0;
constexpr long long OK2   = OQ    + 1572864;   // k
constexpr long long OV2   = OK2   + 1572864;   // v
constexpr long long OATT  = OV2   + 1572864;   // att [96,256,256]
constexpr long long OCTX  = OATT  + 6291456;
constexpr long long OTMP  = OCTX  + 1572864;
constexpr long long OATN  = OTMP  + 1572864;
constexpr long long OINT  = OATN  + 1572864;   // ffn intermediate [2048,3072]
constexpr long long OEE   = OINT  + 6291456;   // edge_emb [51600,200]
constexpr long long OKE   = OEE   + 10320000;  // keyE (also h_ee scratch)
constexpr long long OME   = OKE   + 10320000;  // msgE
constexpr long long OX2   = OME   + 10320000;  // x2 [1600,400]
constexpr long long OKN   = OX2   + 640000;    // keyN
constexpr long long OMN   = OKN   + 320000;    // msgN
constexpr long long OQN   = OMN   + 320000;    // qryN
constexpr long long OSC   = OQN   + 320000;    // scores [51600,4]
constexpr long long OSMX  = OSC   + 206400;    // smax (uint enc)
constexpr long long ODEN  = OSMX  + 6400;
constexpr long long ODEG  = ODEN  + 6400;
constexpr long long OAGG  = ODEG  + 1600;      // aggr [1600,200]
constexpr long long OHM   = OAGG  + 320000;
constexpr long long OXC   = OHM   + 320000;    // Xc working copy
constexpr long long OCF   = OXC   + 320000;    // cf [8,968]
constexpr long long OCF1  = OCF   + 7744;
constexpr long long OCF2  = OCF1  + 1600;
constexpr long long OEESC = OCF2  + 7744;      // ee folded bn scale
constexpr long long OEEBS = OEESC + 200;
constexpr long long OMLSC = OEEBS + 200;       // gat mlp folded (5*200)
constexpr long long OMLBS = OMLSC + 1000;
constexpr long long WSF   = OMLBS + 1000;
}

// ---------------- helpers ----------------
__device__ inline unsigned dk_fenc(float f) {
    unsigned u = __float_as_uint(f);
    return (u & 0x80000000u) ? ~u : (u | 0x80000000u);
}
__device__ inline float dk_fdec(unsigned u) {
    return (u & 0x80000000u) ? __uint_as_float(u & 0x7fffffffu) : __uint_as_float(~u);
}
__device__ inline float dk_gelu(float v) {
    return 0.5f * v * (1.0f + erff(v * 0.70710678118654752f));
}

// ---------------- generic tiled fp32 GEMM ----------------
// C = act( A@B * scale[n] + bias[n] + R ), batched: z = zo*innerB + zi
template<bool TRANSB, int ACT, bool HAS_SCALE, bool HAS_RES>
__global__ __launch_bounds__(256)
void dk_gemm64(const float* __restrict__ A, const float* __restrict__ Bm,
               const float* __restrict__ bias, const float* __restrict__ scale,
               const float* __restrict__ Rm, float* __restrict__ C,
               int M, int N, int K, int lda, int ldb, int ldc,
               int innerB, long long sAo, long long sAi, long long sBo, long long sBi,
               long long sCo, long long sCi)
{
    int z = blockIdx.z;
    int zo = z / innerB, zi = z % innerB;
    A  += (long long)zo * sAo + (long long)zi * sAi;
    Bm += (long long)zo * sBo + (long long)zi * sBi;
    long long coff = (long long)zo * sCo + (long long)zi * sCi;

    __shared__ float As[16][65];
    __shared__ float Bs[16][65];

    int tid = threadIdx.x;
    int tx = tid & 15, ty = tid >> 4;
    int m0 = blockIdx.y * 64, n0 = blockIdx.x * 64;

    float acc[4][4] = {};

    for (int k0 = 0; k0 < K; k0 += 16) {
#pragma unroll
        for (int i = 0; i < 4; i++) {
            int idx = tid + i * 256;
            int r = idx >> 4, c = idx & 15;
            int mm = m0 + r, kk = k0 + c;
            As[c][r] = (mm < M && kk < K) ? A[(long long)mm * lda + kk] : 0.f;
        }
#pragma unroll
        for (int i = 0; i < 4; i++) {
            int idx = tid + i * 256;
            if (!TRANSB) {
                int n = idx & 63, kk = idx >> 6;
                int nn = n0 + n, kx = k0 + kk;
                Bs[kk][n] = (nn < N && kx < K) ? Bm[(long long)kx * ldb + nn] : 0.f;
            } else {
                int kk = idx & 15, n = idx >> 4;
                int nn = n0 + n, kx = k0 + kk;
                Bs[kk][n] = (nn < N && kx < K) ? Bm[(long long)nn * ldb + kx] : 0.f;
            }
        }
        __syncthreads();
#pragma unroll
        for (int kk = 0; kk < 16; kk++) {
            float a[4], b[4];
#pragma unroll
            for (int i = 0; i < 4; i++) a[i] = As[kk][ty * 4 + i];
#pragma unroll
            for (int j = 0; j < 4; j++) b[j] = Bs[kk][tx * 4 + j];
#pragma unroll
            for (int i = 0; i < 4; i++)
#pragma unroll
                for (int j = 0; j < 4; j++) acc[i][j] += a[i] * b[j];
        }
        __syncthreads();
    }

    const float* R = HAS_RES ? (Rm + coff) : nullptr;
    float* Cc = C + coff;
#pragma unroll
    for (int i = 0; i < 4; i++) {
        int mm = m0 + ty * 4 + i;
        if (mm >= M) continue;
#pragma unroll
        for (int j = 0; j < 4; j++) {
            int nn = n0 + tx * 4 + j;
            if (nn >= N) continue;
            float v = acc[i][j];
            if (HAS_SCALE) v *= scale[nn];
            if (bias) v += bias[nn];
            if (HAS_RES) v += R[(long long)mm * ldc + nn];
            if (ACT == 1) v = fmaxf(v, 0.f);
            if (ACT == 2) v = dk_gelu(v);
            Cc[(long long)mm * ldc + nn] = v;
        }
    }
}

// ---------------- attention softmax (row = one (b,h,q)) ----------------
__global__ __launch_bounds__(256)
void dk_att_softmax(float* __restrict__ att, const float* __restrict__ mask)
{
    int row = blockIdx.x;
    int b = row / (CNH * CS);
    int tid = threadIdx.x;
    float x = att[(long long)row * CS + tid] * 0.125f + mask[b * CS + tid];
    __shared__ float red[256];
    red[tid] = x; __syncthreads();
    for (int s = 128; s; s >>= 1) { if (tid < s) red[tid] = fmaxf(red[tid], red[tid + s]); __syncthreads(); }
    float mx = red[0]; __syncthreads();
    float e = expf(x - mx);
    red[tid] = e; __syncthreads();
    for (int s = 128; s; s >>= 1) { if (tid < s) red[tid] += red[tid + s]; __syncthreads(); }
    float sum = red[0];
    att[(long long)row * CS + tid] = e / sum;
}

// ---------------- layernorm over 768 ----------------
__global__ __launch_bounds__(256)
void dk_ln_row(const float* __restrict__ in, const float* __restrict__ w,
               const float* __restrict__ b, float* __restrict__ out)
{
    int row = blockIdx.x, tid = threadIdx.x;
    const float* ip = in + (long long)row * CSD;
    float xv[3];
    float s = 0.f;
#pragma unroll
    for (int t = 0; t < 3; t++) { xv[t] = ip[tid + t * 256]; s += xv[t]; }
    __shared__ float red[256];
    red[tid] = s; __syncthreads();
    for (int st = 128; st; st >>= 1) { if (tid < st) red[tid] += red[tid + st]; __syncthreads(); }
    float mean = red[0] * (1.f / 768.f); __syncthreads();
    float v = 0.f;
#pragma unroll
    for (int t = 0; t < 3; t++) { float d = xv[t] - mean; v += d * d; }
    red[tid] = v; __syncthreads();
    for (int st = 128; st; st >>= 1) { if (tid < st) red[tid] += red[tid + st]; __syncthreads(); }
    float var = red[0] * (1.f / 768.f);
    float rs = 1.0f / sqrtf(var + 1e-12f);
    float* op = out + (long long)row * CSD;
#pragma unroll
    for (int t = 0; t < 3; t++) {
        int c = tid + t * 256;
        op[c] = (xv[t] - mean) * rs * w[c] + b[c];
    }
}

// ---------------- small utility kernels ----------------
__global__ void dk_copy_f32(const float* __restrict__ a, float* __restrict__ o, long long n)
{
    long long i = (long long)blockIdx.x * 256 + threadIdx.x;
    if (i < n) o[i] = a[i];
}

__global__ void dk_fold_bn(const float* __restrict__ b1, const float* __restrict__ bw,
                           const float* __restrict__ bb, float* __restrict__ sc,
                           float* __restrict__ bs, int n)
{
    int i = blockIdx.x * 256 + threadIdx.x;
    if (i >= n) return;
    float c = 1.0f / sqrtf(1.0f + 1e-5f);
    sc[i] = c * bw[i];
    bs[i] = b1[i] * c * bw[i] + bb[i];
}

// edge-encoder layer 1: one-hot gather-sum + folded BN + relu
__global__ __launch_bounds__(256)
void dk_ee_gather(const float* __restrict__ w1, const float* __restrict__ sc,
                  const float* __restrict__ bs, const int* __restrict__ eidx,
                  const int* __restrict__ etyp, const int* __restrict__ ntyp,
                  float* __restrict__ out)
{
    int e = blockIdx.x, d = threadIdx.x;
    if (d >= CD) return;
    int t0, s, t;
    if (e < CE) { t0 = etyp[e]; s = eidx[e]; t = eidx[CE + e]; }
    else        { t0 = CNET; s = t = e - CE; }
    int h0 = ntyp[s], t1 = ntyp[t];
    float v = w1[t0 * CD + d] + w1[(CNET + 1 + h0) * CD + d] + w1[(CNET + 1 + CNNT + t1) * CD + d];
    v = v * sc[d] + bs[d];
    out[(long long)e * CD + d] = fmaxf(v, 0.f);
}

__global__ void dk_deg_init(float* __restrict__ deg)
{
    int i = blockIdx.x * 256 + threadIdx.x;
    if (i < CN) deg[i] = 1.0f;  // self loop
}
__global__ void dk_deg_count(const int* __restrict__ eidx, float* __restrict__ deg)
{
    int e = blockIdx.x * 256 + threadIdx.x;
    if (e < CE) atomicAdd(&deg[eidx[e]], 1.0f);
}

__global__ void dk_x2_build(const float* __restrict__ Xc, const float* __restrict__ nfe,
                            float* __restrict__ x2)
{
    int i = blockIdx.x * 256 + threadIdx.x;
    if (i >= CN * 2 * CD) return;
    int n = i / (2 * CD), d = i % (2 * CD);
    x2[i] = (d < CD) ? Xc[(long long)n * CD + d] : nfe[(long long)n * CD + (d - CD)];
}

__global__ __launch_bounds__(256)
void dk_gat_scores(const float* __restrict__ qryN, const float* __restrict__ keyN,
                   const float* __restrict__ keyE, const int* __restrict__ eidx,
                   float* __restrict__ scores, unsigned* __restrict__ smax)
{
    long long id = (long long)blockIdx.x * 256 + threadIdx.x;
    if (id >= (long long)CEN * CHC) return;
    int e = (int)(id >> 2), h = (int)(id & 3);
    int s, t;
    if (e < CE) { s = eidx[e]; t = eidx[CE + e]; } else { s = t = e - CE; }
    const float* qp = qryN + (long long)s * CD + h * CDPH;
    const float* kp = keyN + (long long)t * CD + h * CDPH;
    const float* ke = keyE + (long long)e * CD + h * CDPH;
    float acc = 0.f;
#pragma unroll 10
    for (int d = 0; d < CDPH; d++) acc += qp[d] * (kp[d] + ke[d]);
    acc *= 0.14142135623730950488f;  // 1/sqrt(50)
    scores[id] = acc;
    atomicMax(&smax[s * CHC + h], dk_fenc(acc));
}

__global__ __launch_bounds__(256)
void dk_gat_expsum(const unsigned* __restrict__ smax, const int* __restrict__ eidx,
                   float* __restrict__ scores, float* __restrict__ den)
{
    long long id = (long long)blockIdx.x * 256 + threadIdx.x;
    if (id >= (long long)CEN * CHC) return;
    int e = (int)(id >> 2), h = (int)(id & 3);
    int s;
    if (e < CE) s = eidx[e]; else s = e - CE;
    float ex = expf(scores[id] - dk_fdec(smax[s * CHC + h]));
    scores[id] = ex;
    atomicAdd(&den[s * CHC + h], ex);
}

__global__ __launch_bounds__(256)
void dk_gat_aggr(const float* __restrict__ msgN, const float* __restrict__ msgE,
                 const float* __restrict__ scores, const float* __restrict__ den,
                 const float* __restrict__ deg, const int* __restrict__ eidx,
                 float* __restrict__ aggr)
{
    int e = blockIdx.x, d = threadIdx.x;
    if (d >= CD) return;
    int s, t;
    if (e < CE) { s = eidx[e]; t = eidx[CE + e]; } else { s = t = e - CE; }
    int h = d / CDPH;
    float alpha = scores[(long long)e * CHC + h] / (den[s * CHC + h] + 1e-16f) * deg[s];
    float v = (msgN[(long long)s * CD + d] + msgE[(long long)e * CD + d]) * alpha;
    atomicAdd(&aggr[(long long)t * CD + d], v);
}

__global__ void dk_cf_build(const float* __restrict__ hs, const float* __restrict__ Xc,
                            float* __restrict__ cf)
{
    int i = blockIdx.x * 256 + threadIdx.x;
    if (i >= CB * (CSD + CD)) return;
    int b = i / (CSD + CD), c = i % (CSD + CD);
    cf[i] = (c < CSD) ? hs[(long long)b * CS * CSD + c]
                      : Xc[(long long)b * CNN * CD + (c - CSD)];
}

__global__ void dk_cf_scatter(const float* __restrict__ cf2, float* __restrict__ hs,
                              float* __restrict__ Xc)
{
    int i = blockIdx.x * 256 + threadIdx.x;
    if (i >= CB * (CSD + CD)) return;
    int b = i / (CSD + CD), c = i % (CSD + CD);
    float v = cf2[i];
    if (c < CSD) hs[(long long)b * CS * CSD + c] = v;
    else         Xc[(long long)b * CNN * CD + (c - CSD)] = v;
}

// ---------------- host-side GEMM dispatch ----------------
static void gemm_go(hipStream_t st, bool transb, int act, bool hasScale, bool hasRes,
                    const float* A, const float* B, const float* bias, const float* scale,
                    const float* R, float* C, int M, int N, int K, int lda, int ldb, int ldc,
                    int batches = 1, int innerB = 1,
                    long long sAo = 0, long long sAi = 0, long long sBo = 0, long long sBi = 0,
                    long long sCo = 0, long long sCi = 0)
{
    dim3 grid((N + 63) / 64, (M + 63) / 64, batches), blk(256);
    if (transb)
        dk_gemm64<true, 0, false, false><<<grid, blk, 0, st>>>(A, B, bias, scale, R, C, M, N, K, lda, ldb, ldc, innerB, sAo, sAi, sBo, sBi, sCo, sCi);
    else if (act == 2)
        dk_gemm64<false, 2, false, false><<<grid, blk, 0, st>>>(A, B, bias, scale, R, C, M, N, K, lda, ldb, ldc, innerB, sAo, sAi, sBo, sBi, sCo, sCi);
    else if (act == 1)
        dk_gemm64<false, 1, true, false><<<grid, blk, 0, st>>>(A, B, bias, scale, R, C, M, N, K, lda, ldb, ldc, innerB, sAo, sAi, sBo, sBi, sCo, sCi);
    else if (hasRes)
        dk_gemm64<false, 0, false, true><<<grid, blk, 0, st>>>(A, B, bias, scale, R, C, M, N, K, lda, ldb, ldc, innerB, sAo, sAi, sBo, sBi, sCo, sCi);
    else
        dk_gemm64<false, 0, false, false><<<grid, blk, 0, st>>>(A, B, bias, scale, R, C, M, N, K, lda, ldb, ldc, innerB, sAo, sAi, sBo, sBi, sCo, sCi);
}

// ---------------- launch ----------------
extern "C" void kernel_launch(void* const* d_in, const int* in_sizes, int n_in,
                              void* d_out, int out_size, void* d_ws, size_t ws_size,
                              hipStream_t stream)
{
    const float* hidden = (const float*)d_in[0];
    const float* amask  = (const float*)d_in[1];
    const float* Xin    = (const float*)d_in[2];
    const float* nfe    = (const float*)d_in[3];
    const float* qkv_w  = (const float*)d_in[4];
    const float* qkv_b  = (const float*)d_in[5];
    const float* aow    = (const float*)d_in[6];
    const float* aob    = (const float*)d_in[7];
    const float* ln1w   = (const float*)d_in[8];
    const float* ln1b   = (const float*)d_in[9];
    const float* f1w    = (const float*)d_in[10];
    const float* f1b    = (const float*)d_in[11];
    const float* f2w    = (const float*)d_in[12];
    const float* f2b    = (const float*)d_in[13];
    const float* ln2w   = (const float*)d_in[14];
    const float* ln2b   = (const float*)d_in[15];
    const float* eew1   = (const float*)d_in[16];
    const float* eeb1   = (const float*)d_in[17];
    const float* eebnw  = (const float*)d_in[18];
    const float* eebnb  = (const float*)d_in[19];
    const float* eew2   = (const float*)d_in[20];
    const float* eeb2   = (const float*)d_in[21];
    const float* gkw    = (const float*)d_in[22];
    const float* gkb    = (const float*)d_in[23];
    const float* gmw    = (const float*)d_in[24];
    const float* gmb    = (const float*)d_in[25];
    const float* gqw    = (const float*)d_in[26];
    const float* gqb    = (const float*)d_in[27];
    const float* mw1    = (const float*)d_in[28];
    const float* mb1    = (const float*)d_in[29];
    const float* mbnw   = (const float*)d_in[30];
    const float* mbnb   = (const float*)d_in[31];
    const float* mw2    = (const float*)d_in[32];
    const float* mb2    = (const float*)d_in[33];
    const float* iew1   = (const float*)d_in[34];
    const float* ieb1   = (const float*)d_in[35];
    const float* iew2   = (const float*)d_in[36];
    const float* ieb2   = (const float*)d_in[37];
    const int*   eidx   = (const int*)d_in[38];
    const int*   etyp   = (const int*)d_in[39];
    const int*   ntyp   = (const int*)d_in[40];

    float* hs    = (float*)d_out;                         // [2048,768] working + output
    float* XcOut = hs + (long long)CB * CS * CSD;         // output tail [1600,200]

    float* w = (float*)d_ws;
    float* qb   = w + OQ;
    float* kb   = w + OK2;
    float* vb   = w + OV2;
    float* attb = w + OATT;
    float* ctx  = w + OCTX;
    float* tmp  = w + OTMP;
    float* atn  = w + OATN;
    float* inter= w + OINT;
    float* eemb = w + OEE;
    float* keyE = w + OKE;   // doubles as h_ee scratch during precompute
    float* msgE = w + OME;
    float* x2   = w + OX2;
    float* keyN = w + OKN;
    float* msgN = w + OMN;
    float* qryN = w + OQN;
    float* scrs = w + OSC;
    unsigned* smax = (unsigned*)(w + OSMX);
    float* den  = w + ODEN;
    float* deg  = w + ODEG;
    float* aggr = w + OAGG;
    float* hm   = w + OHM;
    float* Xc   = w + OXC;
    float* cf   = w + OCF;
    float* cf1  = w + OCF1;
    float* cf2  = w + OCF2;
    float* eeSc = w + OEESC;
    float* eeBs = w + OEEBS;
    float* mlSc = w + OMLSC;
    float* mlBs = w + OMLBS;

    const long long HS_N = (long long)CB * CS * CSD;   // 1,572,864
    const long long XC_N = (long long)CN * CD;         // 320,000

    // ---- init ----
    dk_copy_f32<<<(unsigned)((HS_N + 255) / 256), 256, 0, stream>>>(hidden, hs, HS_N);
    dk_copy_f32<<<(unsigned)((XC_N + 255) / 256), 256, 0, stream>>>(Xin, Xc, XC_N);
    dk_fold_bn<<<1, 256, 0, stream>>>(eeb1, eebnw, eebnb, eeSc, eeBs, CD);
    dk_fold_bn<<<4, 256, 0, stream>>>(mb1, mbnw, mbnb, mlSc, mlBs, CK * CD);

    // ---- edge embeddings (shared across GAT layers) ----
    dk_ee_gather<<<CEN, 256, 0, stream>>>(eew1, eeSc, eeBs, eidx, etyp, ntyp, keyE /*h_ee*/);
    gemm_go(stream, false, 0, false, false, keyE, eew2, eeb2, nullptr, nullptr, eemb,
            CEN, CD, CD, CD, CD, CD);

    // ---- degree (incl. self loop) ----
    dk_deg_init<<<(CN + 255) / 256, 256, 0, stream>>>(deg);
    dk_deg_count<<<(CE + 255) / 256, 256, 0, stream>>>(eidx, deg);

    const long long sBH = (long long)CS * CSD;  // per-batch stride in q/k/v/ctx
    const long long sAT = (long long)CNH * CS * CS;

    for (int i = 0; i < CL; i++) {
        // qkv
        for (int t = 0; t < 3; t++) {
            float* dst = (t == 0) ? qb : (t == 1) ? kb : vb;
            gemm_go(stream, false, 0, false, false, hs,
                    qkv_w + ((long long)(i * 3 + t)) * CSD * CSD,
                    qkv_b + (long long)(i * 3 + t) * CSD, nullptr, nullptr, dst,
                    CB * CS, CSD, CSD, CSD, CSD, CSD);
        }
        // scores = q @ k^T  (batched over b,h)
        gemm_go(stream, true, 0, false, false, qb, kb, nullptr, nullptr, nullptr, attb,
                CS, CS, CDH, CSD, CSD, CS,
                CB * CNH, CNH, sBH, CDH, sBH, CDH, sAT, (long long)CS * CS);
        dk_att_softmax<<<CB * CNH * CS, 256, 0, stream>>>(attb, amask);
        // ctx = att @ v
        gemm_go(stream, false, 0, false, false, attb, vb, nullptr, nullptr, nullptr, ctx,
                CS, CDH, CS, CS, CSD, CSD,
                CB * CNH, CNH, sAT, (long long)CS * CS, sBH, CDH, sBH, CDH);
        // out proj + residual, then LN1
        gemm_go(stream, false, 0, false, true, ctx, aow + (long long)i * CSD * CSD,
                aob + (long long)i * CSD, nullptr, hs, tmp, CB * CS, CSD, CSD, CSD, CSD, CSD);
        dk_ln_row<<<CB * CS, 256, 0, stream>>>(tmp, ln1w + (long long)i * CSD, ln1b + (long long)i * CSD, atn);
        // ffn
        gemm_go(stream, false, 2, false, false, atn, f1w + (long long)i * CSD * CFF,
                f1b + (long long)i * CFF, nullptr, nullptr, inter, CB * CS, CFF, CSD, CSD, CFF, CFF);
        gemm_go(stream, false, 0, false, true, inter, f2w + (long long)i * CFF * CSD,
                f2b + (long long)i * CSD, nullptr, atn, tmp, CB * CS, CSD, CFF, CFF, CSD, CSD);
        dk_ln_row<<<CB * CS, 256, 0, stream>>>(tmp, ln2w + (long long)i * CSD, ln2b + (long long)i * CSD, hs);

        if (i >= CL - CK) {
            int g = i - (CL - CK);
            // node-level projections
            dk_x2_build<<<(CN * 2 * CD + 255) / 256, 256, 0, stream>>>(Xc, nfe, x2);
            gemm_go(stream, false, 0, false, false, x2, gqw + (long long)g * 2 * CD * CD,
                    gqb + (long long)g * CD, nullptr, nullptr, qryN, CN, CD, 2 * CD, 2 * CD, CD, CD);
            gemm_go(stream, false, 0, false, false, x2, gkw + (long long)g * 3 * CD * CD,
                    gkb + (long long)g * CD, nullptr, nullptr, keyN, CN, CD, 2 * CD, 2 * CD, CD, CD);
            gemm_go(stream, false, 0, false, false, x2, gmw + (long long)g * 3 * CD * CD,
                    gmb + (long long)g * CD, nullptr, nullptr, msgN, CN, CD, 2 * CD, 2 * CD, CD, CD);
            // edge-level projections (rows 400..599 of W)
            gemm_go(stream, false, 0, false, false, eemb,
                    gkw + (long long)g * 3 * CD * CD + (long long)2 * CD * CD,
                    nullptr, nullptr, nullptr, keyE, CEN, CD, CD, CD, CD, CD);
            gemm_go(stream, false, 0, false, false, eemb,
                    gmw + (long long)g * 3 * CD * CD + (long long)2 * CD * CD,
                    nullptr, nullptr, nullptr, msgE, CEN, CD, CD, CD, CD, CD);
            // segment softmax + aggregate
            hipMemsetAsync(smax, 0, CN * CHC * sizeof(unsigned), stream);
            hipMemsetAsync(den, 0, CN * CHC * sizeof(float), stream);
            hipMemsetAsync(aggr, 0, (size_t)CN * CD * sizeof(float), stream);
            dk_gat_scores<<<(CEN * CHC + 255) / 256, 256, 0, stream>>>(qryN, keyN, keyE, eidx, scrs, smax);
            dk_gat_expsum<<<(CEN * CHC + 255) / 256, 256, 0, stream>>>(smax, eidx, scrs, den);
            dk_gat_aggr<<<CEN, 256, 0, stream>>>(msgN, msgE, scrs, den, deg, eidx, aggr);
            // mlp: relu(bn(aggr@w1+b1)) @ w2 + b2, then gelu -> Xc
            gemm_go(stream, false, 1, true, false, aggr, mw1 + (long long)g * CD * CD,
                    mlBs + (long long)g * CD, mlSc + (long long)g * CD, nullptr, hm,
                    CN, CD, CD, CD, CD, CD);
            gemm_go(stream, false, 2, false, false, hm, mw2 + (long long)g * CD * CD,
                    mb2 + (long long)g * CD, nullptr, nullptr, Xc, CN, CD, CD, CD, CD, CD);
            // info exchange
            dk_cf_build<<<(CB * (CSD + CD) + 255) / 256, 256, 0, stream>>>(hs, Xc, cf);
            gemm_go(stream, false, 2, false, false, cf, iew1, ieb1, nullptr, nullptr, cf1,
                    CB, CIE, CSD + CD, CSD + CD, CIE, CIE);
            gemm_go(stream, false, 0, false, false, cf1, iew2, ieb2, nullptr, nullptr, cf2,
                    CB, CSD + CD, CIE, CIE, CSD + CD, CSD + CD);
            dk_cf_scatter<<<(CB * (CSD + CD) + 255) / 256, 256, 0, stream>>>(cf2, hs, Xc);
        }
    }

    dk_copy_f32<<<(unsigned)((XC_N + 255) / 256), 256, 0, stream>>>(Xc, XcOut, XC_N);
}

// Round 2
// 9183.743 us; speedup vs baseline: 2.7031x; 2.7031x over previous
//
#include <hip/hip_runtime.h>
#include <math.h>

// ---------------- problem constants ----------------
namespace {
constexpr int CB = 8, CS = 256, CSD = 768, CL = 12, CNH = 12, CDH = 64, CFF = 3072;
constexpr int CK = 5, CD = 200, CHC = 4, CDPH = 50, CNNT = 4, CNET = 38;
constexpr int CNN = 200, CN = 1600, CE = 50000, CEN = 51600, CIE = 200;

// workspace offsets (floats)
constexpr long long OQ    = 0;
constexpr long long OK2   = OQ    + 1572864;   // k
constexpr long long OV2   = OK2   + 1572864;   // v
constexpr long long OATT  = OV2   + 1572864;   // att [96,256,256]
constexpr long long OCTX  = OATT  + 6291456;
constexpr long long OTMP  = OCTX  + 1572864;
constexpr long long OATN  = OTMP  + 1572864;
constexpr long long OINT  = OATN  + 1572864;   // ffn intermediate [2048,3072]
constexpr long long OEE   = OINT  + 6291456;   // edge_emb [51600,200]
constexpr long long OKE   = OEE   + 10320000;  // keyE (also h_ee scratch)
constexpr long long OME   = OKE   + 10320000;  // msgE
constexpr long long OX2   = OME   + 10320000;  // x2 [1600,400]
constexpr long long OKN   = OX2   + 640000;    // keyN
constexpr long long OMN   = OKN   + 320000;    // msgN
constexpr long long OQN   = OMN   + 320000;    // qryN
constexpr long long OSC   = OQN   + 320000;    // scores [51600,4]
constexpr long long OSMX  = OSC   + 206400;    // smax (uint enc)
constexpr long long ODEN  = OSMX  + 6400;
constexpr long long ODEG  = ODEN  + 6400;
constexpr long long OAGG  = ODEG  + 1600;      // aggr [1600,200]
constexpr long long OHM   = OAGG  + 320000;
constexpr long long OXC   = OHM   + 320000;    // Xc working copy
constexpr long long OCF   = OXC   + 320000;    // cf [8,968]
constexpr long long OCF1  = OCF   + 7744;
constexpr long long OCF2  = OCF1  + 1600;
constexpr long long OEESC = OCF2  + 7744;      // ee folded bn scale
constexpr long long OEEBS = OEESC + 200;
constexpr long long OMLSC = OEEBS + 200;       // gat mlp folded (5*200)
constexpr long long OMLBS = OMLSC + 1000;
}

typedef __attribute__((ext_vector_type(8))) short bh8;
typedef __attribute__((ext_vector_type(4))) float fx4;

// ---------------- helpers ----------------
__device__ inline unsigned dk_fenc(float f) {
    unsigned u = __float_as_uint(f);
    return (u & 0x80000000u) ? ~u : (u | 0x80000000u);
}
__device__ inline float dk_fdec(unsigned u) {
    return (u & 0x80000000u) ? __uint_as_float(u & 0x7fffffffu) : __uint_as_float(~u);
}
__device__ inline float dk_gelu(float v) {
    return 0.5f * v * (1.0f + erff(v * 0.70710678118654752f));
}
__device__ inline short dk_f2bf(float f) {
    unsigned u = __float_as_uint(f);
    unsigned r = (u + 0x7fffu + ((u >> 16) & 1u)) >> 16;
    return (short)r;
}

// ---------------- bf16 MFMA GEMM: 128x128 tile, BK=32, 4 waves ----------------
// C = act( A@B * scale[n] + bias[z][n] + R ), batched z = zo*innerB + zi.
// A fp32 [M,K] (lda), B fp32: TRANSB ? [N,K] (ldb) : [K,N] (ldb). K%8==0 assumed.
template<bool TRANSB, int ACT, bool HAS_SCALE, bool HAS_RES>
__global__ __launch_bounds__(256)
void dk_mgemm(const float* __restrict__ A, const float* __restrict__ Bm,
              const float* __restrict__ bias, long long sBias,
              const float* __restrict__ scale, const float* __restrict__ Rm,
              float* __restrict__ C,
              int M, int N, int K, int lda, int ldb, int ldc,
              int innerB, long long sAo, long long sAi, long long sBo, long long sBi,
              long long sCo, long long sCi)
{
    int z = blockIdx.z;
    int zo = z / innerB, zi = z - zo * innerB;
    A  += (long long)zo * sAo + (long long)zi * sAi;
    Bm += (long long)zo * sBo + (long long)zi * sBi;
    const float* biasp = bias ? (bias + (long long)z * sBias) : nullptr;
    long long coff = (long long)zo * sCo + (long long)zi * sCi;

    __shared__ __align__(16) short As[128 * 32];
    __shared__ __align__(16) short Bs[128 * 32];

    int tid = threadIdx.x;
    int m0 = blockIdx.y * 128, n0 = blockIdx.x * 128;

    int l = tid & 63, w = tid >> 6;
    int wm = (w >> 1) * 64, wn = (w & 1) * 64;
    int lr = l & 15, lkB = (l >> 4) * 16;   // byte offset of k-slice within row

    fx4 acc[4][4] = {};

    // staging registers
    bh8 ra0, ra1, rb0, rb1;

    // ---- load helpers ----
    // A-side (also TRANSB B-side): row-major [rows, K], contiguous k
    auto loadRowK = [&](const float* P, int r0, int r, int kk, int Rows, int ld) -> bh8 {
        bh8 s;
        if ((r0 + r) < Rows && kk + 8 <= K) {
            const float4* p = reinterpret_cast<const float4*>(P + (long long)(r0 + r) * ld + kk);
            float4 a = p[0], b = p[1];
            s[0] = dk_f2bf(a.x); s[1] = dk_f2bf(a.y); s[2] = dk_f2bf(a.z); s[3] = dk_f2bf(a.w);
            s[4] = dk_f2bf(b.x); s[5] = dk_f2bf(b.y); s[6] = dk_f2bf(b.z); s[7] = dk_f2bf(b.w);
        } else {
#pragma unroll
            for (int j = 0; j < 8; j++) s[j] = 0;
        }
        return s;
    };
    // B non-trans: [K, N], strided along k
    auto loadKN = [&](int n, int kk) -> bh8 {
        bh8 s;
        if ((n0 + n) < N && kk + 8 <= K) {
            const float* p = Bm + (long long)kk * ldb + (n0 + n);
#pragma unroll
            for (int j = 0; j < 8; j++) s[j] = dk_f2bf(p[(long long)j * ldb]);
        } else {
#pragma unroll
            for (int j = 0; j < 8; j++) s[j] = 0;
        }
        return s;
    };

    int arow = tid >> 2, akcB = (tid & 3) * 16;             // A chunk mapping
    int bn_nt = tid & 127, bkcI = tid >> 7;                 // B non-trans mapping

    auto gload = [&](int k0) {
        ra0 = loadRowK(A, m0, arow, k0 + (tid & 3) * 8, M, lda);
        ra1 = loadRowK(A, m0, arow + 64, k0 + (tid & 3) * 8, M, lda);
        if (TRANSB) {
            rb0 = loadRowK(Bm, n0, arow, k0 + (tid & 3) * 8, N, ldb);
            rb1 = loadRowK(Bm, n0, arow + 64, k0 + (tid & 3) * 8, N, ldb);
        } else {
            rb0 = loadKN(bn_nt, k0 + bkcI * 8);
            rb1 = loadKN(bn_nt, k0 + bkcI * 8 + 16);
        }
    };
    auto swz = [](int row) { return ((row >> 1) & 3) << 4; };
    auto dswrite = [&]() {
        *(bh8*)((char*)As + arow * 64 + (akcB ^ swz(arow))) = ra0;
        *(bh8*)((char*)As + (arow + 64) * 64 + (akcB ^ swz(arow + 64))) = ra1;
        if (TRANSB) {
            *(bh8*)((char*)Bs + arow * 64 + (akcB ^ swz(arow))) = rb0;
            *(bh8*)((char*)Bs + (arow + 64) * 64 + (akcB ^ swz(arow + 64))) = rb1;
        } else {
            *(bh8*)((char*)Bs + bn_nt * 64 + ((bkcI * 16) ^ swz(bn_nt))) = rb0;
            *(bh8*)((char*)Bs + bn_nt * 64 + ((bkcI * 16 + 32) ^ swz(bn_nt))) = rb1;
        }
    };

    int NT = (K + 31) / 32;
    gload(0);
    for (int t = 0; t < NT; ++t) {
        __syncthreads();
        dswrite();
        __syncthreads();
        if (t + 1 < NT) gload((t + 1) * 32);

        bh8 af[4], bf[4];
#pragma unroll
        for (int mi = 0; mi < 4; mi++) {
            int ra = wm + mi * 16 + lr;
            af[mi] = *(const bh8*)((const char*)As + ra * 64 + (lkB ^ swz(ra)));
        }
#pragma unroll
        for (int ni = 0; ni < 4; ni++) {
            int rb = wn + ni * 16 + lr;
            bf[ni] = *(const bh8*)((const char*)Bs + rb * 64 + (lkB ^ swz(rb)));
        }
#pragma unroll
        for (int mi = 0; mi < 4; mi++)
#pragma unroll
            for (int ni = 0; ni < 4; ni++)
                acc[mi][ni] = __builtin_amdgcn_mfma_f32_16x16x32_bf16(af[mi], bf[ni], acc[mi][ni], 0, 0, 0);
    }

    // ---- epilogue ----
    const float* R = HAS_RES ? (Rm + coff) : nullptr;
    float* Cc = C + coff;
#pragma unroll
    for (int ni = 0; ni < 4; ni++) {
        int nn = n0 + wn + ni * 16 + lr;
        if (nn >= N) continue;
        float sc = HAS_SCALE ? scale[nn] : 1.0f;
        float bi = biasp ? biasp[nn] : 0.0f;
#pragma unroll
        for (int mi = 0; mi < 4; mi++) {
#pragma unroll
            for (int r = 0; r < 4; r++) {
                int mm = m0 + wm + mi * 16 + (l >> 4) * 4 + r;
                if (mm >= M) continue;
                float v = acc[mi][ni][r];
                if (HAS_SCALE) v *= sc;
                v += bi;
                if (HAS_RES) v += R[(long long)mm * ldc + nn];
                if (ACT == 1) v = fmaxf(v, 0.f);
                if (ACT == 2) v = dk_gelu(v);
                Cc[(long long)mm * ldc + nn] = v;
            }
        }
    }
}

// ---------------- fp32 fallback GEMM (tiny shapes) ----------------
template<int ACT>
__global__ __launch_bounds__(256)
void dk_gemm64(const float* __restrict__ A, const float* __restrict__ Bm,
               const float* __restrict__ bias, float* __restrict__ C,
               int M, int N, int K, int lda, int ldb, int ldc)
{
    __shared__ float As[16][65];
    __shared__ float Bs[16][65];
    int tid = threadIdx.x;
    int tx = tid & 15, ty = tid >> 4;
    int m0 = blockIdx.y * 64, n0 = blockIdx.x * 64;
    float acc[4][4] = {};
    for (int k0 = 0; k0 < K; k0 += 16) {
#pragma unroll
        for (int i = 0; i < 4; i++) {
            int idx = tid + i * 256;
            int r = idx >> 4, c = idx & 15;
            int mm = m0 + r, kk = k0 + c;
            As[c][r] = (mm < M && kk < K) ? A[(long long)mm * lda + kk] : 0.f;
        }
#pragma unroll
        for (int i = 0; i < 4; i++) {
            int idx = tid + i * 256;
            int n = idx & 63, kk = idx >> 6;
            int nn = n0 + n, kx = k0 + kk;
            Bs[kk][n] = (nn < N && kx < K) ? Bm[(long long)kx * ldb + nn] : 0.f;
        }
        __syncthreads();
#pragma unroll
        for (int kk = 0; kk < 16; kk++) {
            float a[4], b[4];
#pragma unroll
            for (int i = 0; i < 4; i++) a[i] = As[kk][ty * 4 + i];
#pragma unroll
            for (int j = 0; j < 4; j++) b[j] = Bs[kk][tx * 4 + j];
#pragma unroll
            for (int i = 0; i < 4; i++)
#pragma unroll
                for (int j = 0; j < 4; j++) acc[i][j] += a[i] * b[j];
        }
        __syncthreads();
    }
#pragma unroll
    for (int i = 0; i < 4; i++) {
        int mm = m0 + ty * 4 + i;
        if (mm >= M) continue;
#pragma unroll
        for (int j = 0; j < 4; j++) {
            int nn = n0 + tx * 4 + j;
            if (nn >= N) continue;
            float v = acc[i][j];
            if (bias) v += bias[nn];
            if (ACT == 2) v = dk_gelu(v);
            C[(long long)mm * ldc + nn] = v;
        }
    }
}

// ---------------- attention softmax (row = one (b,h,q)) ----------------
__global__ __launch_bounds__(256)
void dk_att_softmax(float* __restrict__ att, const float* __restrict__ mask)
{
    int row = blockIdx.x;
    int b = row / (CNH * CS);
    int tid = threadIdx.x;
    float x = att[(long long)row * CS + tid] * 0.125f + mask[b * CS + tid];
    __shared__ float red[256];
    red[tid] = x; __syncthreads();
    for (int s = 128; s; s >>= 1) { if (tid < s) red[tid] = fmaxf(red[tid], red[tid + s]); __syncthreads(); }
    float mx = red[0]; __syncthreads();
    float e = expf(x - mx);
    red[tid] = e; __syncthreads();
    for (int s = 128; s; s >>= 1) { if (tid < s) red[tid] += red[tid + s]; __syncthreads(); }
    float sum = red[0];
    att[(long long)row * CS + tid] = e / sum;
}

// ---------------- layernorm over 768 ----------------
__global__ __launch_bounds__(256)
void dk_ln_row(const float* __restrict__ in, const float* __restrict__ w,
               const float* __restrict__ b, float* __restrict__ out)
{
    int row = blockIdx.x, tid = threadIdx.x;
    const float* ip = in + (long long)row * CSD;
    float xv[3];
    float s = 0.f;
#pragma unroll
    for (int t = 0; t < 3; t++) { xv[t] = ip[tid + t * 256]; s += xv[t]; }
    __shared__ float red[256];
    red[tid] = s; __syncthreads();
    for (int st = 128; st; st >>= 1) { if (tid < st) red[tid] += red[tid + st]; __syncthreads(); }
    float mean = red[0] * (1.f / 768.f); __syncthreads();
    float v = 0.f;
#pragma unroll
    for (int t = 0; t < 3; t++) { float d = xv[t] - mean; v += d * d; }
    red[tid] = v; __syncthreads();
    for (int st = 128; st; st >>= 1) { if (tid < st) red[tid] += red[tid + st]; __syncthreads(); }
    float var = red[0] * (1.f / 768.f);
    float rs = 1.0f / sqrtf(var + 1e-12f);
    float* op = out + (long long)row * CSD;
#pragma unroll
    for (int t = 0; t < 3; t++) {
        int c = tid + t * 256;
        op[c] = (xv[t] - mean) * rs * w[c] + b[c];
    }
}

// ---------------- small utility kernels ----------------
__global__ void dk_copy_f32(const float* __restrict__ a, float* __restrict__ o, long long n)
{
    long long i = (long long)blockIdx.x * 256 + threadIdx.x;
    if (i < n) o[i] = a[i];
}

__global__ void dk_fold_bn(const float* __restrict__ b1, const float* __restrict__ bw,
                           const float* __restrict__ bb, float* __restrict__ sc,
                           float* __restrict__ bs, int n)
{
    int i = blockIdx.x * 256 + threadIdx.x;
    if (i >= n) return;
    float c = 1.0f / sqrtf(1.0f + 1e-5f);
    sc[i] = c * bw[i];
    bs[i] = b1[i] * c * bw[i] + bb[i];
}

__global__ __launch_bounds__(256)
void dk_ee_gather(const float* __restrict__ w1, const float* __restrict__ sc,
                  const float* __restrict__ bs, const int* __restrict__ eidx,
                  const int* __restrict__ etyp, const int* __restrict__ ntyp,
                  float* __restrict__ out)
{
    int e = blockIdx.x, d = threadIdx.x;
    if (d >= CD) return;
    int t0, s, t;
    if (e < CE) { t0 = etyp[e]; s = eidx[e]; t = eidx[CE + e]; }
    else        { t0 = CNET; s = t = e - CE; }
    int h0 = ntyp[s], t1 = ntyp[t];
    float v = w1[t0 * CD + d] + w1[(CNET + 1 + h0) * CD + d] + w1[(CNET + 1 + CNNT + t1) * CD + d];
    v = v * sc[d] + bs[d];
    out[(long long)e * CD + d] = fmaxf(v, 0.f);
}

__global__ void dk_deg_init(float* __restrict__ deg)
{
    int i = blockIdx.x * 256 + threadIdx.x;
    if (i < CN) deg[i] = 1.0f;
}
__global__ void dk_deg_count(const int* __restrict__ eidx, float* __restrict__ deg)
{
    int e = blockIdx.x * 256 + threadIdx.x;
    if (e < CE) atomicAdd(&deg[eidx[e]], 1.0f);
}

__global__ void dk_x2_build(const float* __restrict__ Xc, const float* __restrict__ nfe,
                            float* __restrict__ x2)
{
    int i = blockIdx.x * 256 + threadIdx.x;
    if (i >= CN * 2 * CD) return;
    int n = i / (2 * CD), d = i % (2 * CD);
    x2[i] = (d < CD) ? Xc[(long long)n * CD + d] : nfe[(long long)n * CD + (d - CD)];
}

__global__ __launch_bounds__(256)
void dk_gat_scores(const float* __restrict__ qryN, const float* __restrict__ keyN,
                   const float* __restrict__ keyE, const int* __restrict__ eidx,
                   float* __restrict__ scores, unsigned* __restrict__ smax)
{
    long long id = (long long)blockIdx.x * 256 + threadIdx.x;
    if (id >= (long long)CEN * CHC) return;
    int e = (int)(id >> 2), h = (int)(id & 3);
    int s, t;
    if (e < CE) { s = eidx[e]; t = eidx[CE + e]; } else { s = t = e - CE; }
    const float* qp = qryN + (long long)s * CD + h * CDPH;
    const float* kp = keyN + (long long)t * CD + h * CDPH;
    const float* ke = keyE + (long long)e * CD + h * CDPH;
    float acc = 0.f;
#pragma unroll 10
    for (int d = 0; d < CDPH; d++) acc += qp[d] * (kp[d] + ke[d]);
    acc *= 0.14142135623730950488f;
    scores[id] = acc;
    atomicMax(&smax[s * CHC + h], dk_fenc(acc));
}

__global__ __launch_bounds__(256)
void dk_gat_expsum(const unsigned* __restrict__ smax, const int* __restrict__ eidx,
                   float* __restrict__ scores, float* __restrict__ den)
{
    long long id = (long long)blockIdx.x * 256 + threadIdx.x;
    if (id >= (long long)CEN * CHC) return;
    int e = (int)(id >> 2), h = (int)(id & 3);
    int s;
    if (e < CE) s = eidx[e]; else s = e - CE;
    float ex = expf(scores[id] - dk_fdec(smax[s * CHC + h]));
    scores[id] = ex;
    atomicAdd(&den[s * CHC + h], ex);
}

__global__ __launch_bounds__(256)
void dk_gat_aggr(const float* __restrict__ msgN, const float* __restrict__ msgE,
                 const float* __restrict__ scores, const float* __restrict__ den,
                 const float* __restrict__ deg, const int* __restrict__ eidx,
                 float* __restrict__ aggr)
{
    int e = blockIdx.x, d = threadIdx.x;
    if (d >= CD) return;
    int s, t;
    if (e < CE) { s = eidx[e]; t = eidx[CE + e]; } else { s = t = e - CE; }
    int h = d / CDPH;
    float alpha = scores[(long long)e * CHC + h] / (den[s * CHC + h] + 1e-16f) * deg[s];
    float v = (msgN[(long long)s * CD + d] + msgE[(long long)e * CD + d]) * alpha;
    atomicAdd(&aggr[(long long)t * CD + d], v);
}

__global__ void dk_cf_build(const float* __restrict__ hs, const float* __restrict__ Xc,
                            float* __restrict__ cf)
{
    int i = blockIdx.x * 256 + threadIdx.x;
    if (i >= CB * (CSD + CD)) return;
    int b = i / (CSD + CD), c = i % (CSD + CD);
    cf[i] = (c < CSD) ? hs[(long long)b * CS * CSD + c]
                      : Xc[(long long)b * CNN * CD + (c - CSD)];
}

__global__ void dk_cf_scatter(const float* __restrict__ cf2, float* __restrict__ hs,
                              float* __restrict__ Xc)
{
    int i = blockIdx.x * 256 + threadIdx.x;
    if (i >= CB * (CSD + CD)) return;
    int b = i / (CSD + CD), c = i % (CSD + CD);
    float v = cf2[i];
    if (c < CSD) hs[(long long)b * CS * CSD + c] = v;
    else         Xc[(long long)b * CNN * CD + (c - CSD)] = v;
}

// ---------------- host-side MFMA GEMM dispatch ----------------
// mode: 0=plain, 1=transb, 2=res, 3=gelu, 4=relu+scale
static void mgemm_go(hipStream_t st, int mode,
                     const float* A, const float* B, const float* bias, long long sBias,
                     const float* scale, const float* R, float* C,
                     int M, int N, int K, int lda, int ldb, int ldc,
                     int batches = 1, int innerB = 1,
                     long long sAo = 0, long long sAi = 0, long long sBo = 0, long long sBi = 0,
                     long long sCo = 0, long long sCi = 0)
{
    dim3 grid((N + 127) / 128, (M + 127) / 128, batches), blk(256);
    switch (mode) {
    case 0: dk_mgemm<false, 0, false, false><<<grid, blk, 0, st>>>(A, B, bias, sBias, scale, R, C, M, N, K, lda, ldb, ldc, innerB, sAo, sAi, sBo, sBi, sCo, sCi); break;
    case 1: dk_mgemm<true,  0, false, false><<<grid, blk, 0, st>>>(A, B, bias, sBias, scale, R, C, M, N, K, lda, ldb, ldc, innerB, sAo, sAi, sBo, sBi, sCo, sCi); break;
    case 2: dk_mgemm<false, 0, false, true ><<<grid, blk, 0, st>>>(A, B, bias, sBias, scale, R, C, M, N, K, lda, ldb, ldc, innerB, sAo, sAi, sBo, sBi, sCo, sCi); break;
    case 3: dk_mgemm<false, 2, false, false><<<grid, blk, 0, st>>>(A, B, bias, sBias, scale, R, C, M, N, K, lda, ldb, ldc, innerB, sAo, sAi, sBo, sBi, sCo, sCi); break;
    case 4: dk_mgemm<false, 1, true,  false><<<grid, blk, 0, st>>>(A, B, bias, sBias, scale, R, C, M, N, K, lda, ldb, ldc, innerB, sAo, sAi, sBo, sBi, sCo, sCi); break;
    }
}

// ---------------- launch ----------------
extern "C" void kernel_launch(void* const* d_in, const int* in_sizes, int n_in,
                              void* d_out, int out_size, void* d_ws, size_t ws_size,
                              hipStream_t stream)
{
    const float* hidden = (const float*)d_in[0];
    const float* amask  = (const float*)d_in[1];
    const float* Xin    = (const float*)d_in[2];
    const float* nfe    = (const float*)d_in[3];
    const float* qkv_w  = (const float*)d_in[4];
    const float* qkv_b  = (const float*)d_in[5];
    const float* aow    = (const float*)d_in[6];
    const float* aob    = (const float*)d_in[7];
    const float* ln1w   = (const float*)d_in[8];
    const float* ln1b   = (const float*)d_in[9];
    const float* f1w    = (const float*)d_in[10];
    const float* f1b    = (const float*)d_in[11];
    const float* f2w    = (const float*)d_in[12];
    const float* f2b    = (const float*)d_in[13];
    const float* ln2w   = (const float*)d_in[14];
    const float* ln2b   = (const float*)d_in[15];
    const float* eew1   = (const float*)d_in[16];
    const float* eeb1   = (const float*)d_in[17];
    const float* eebnw  = (const float*)d_in[18];
    const float* eebnb  = (const float*)d_in[19];
    const float* eew2   = (const float*)d_in[20];
    const float* eeb2   = (const float*)d_in[21];
    const float* gkw    = (const float*)d_in[22];
    const float* gkb    = (const float*)d_in[23];
    const float* gmw    = (const float*)d_in[24];
    const float* gmb    = (const float*)d_in[25];
    const float* gqw    = (const float*)d_in[26];
    const float* gqb    = (const float*)d_in[27];
    const float* mw1    = (const float*)d_in[28];
    const float* mb1    = (const float*)d_in[29];
    const float* mbnw   = (const float*)d_in[30];
    const float* mbnb   = (const float*)d_in[31];
    const float* mw2    = (const float*)d_in[32];
    const float* mb2    = (const float*)d_in[33];
    const float* iew1   = (const float*)d_in[34];
    const float* ieb1   = (const float*)d_in[35];
    const float* iew2   = (const float*)d_in[36];
    const float* ieb2   = (const float*)d_in[37];
    const int*   eidx   = (const int*)d_in[38];
    const int*   etyp   = (const int*)d_in[39];
    const int*   ntyp   = (const int*)d_in[40];

    float* hs    = (float*)d_out;
    float* XcOut = hs + (long long)CB * CS * CSD;

    float* w = (float*)d_ws;
    float* qb   = w + OQ;
    float* kb   = w + OK2;
    float* vb   = w + OV2;
    float* attb = w + OATT;
    float* ctx  = w + OCTX;
    float* tmp  = w + OTMP;
    float* atn  = w + OATN;
    float* inter= w + OINT;
    float* eemb = w + OEE;
    float* keyE = w + OKE;
    float* msgE = w + OME;
    float* x2   = w + OX2;
    float* keyN = w + OKN;
    float* msgN = w + OMN;
    float* qryN = w + OQN;
    float* scrs = w + OSC;
    unsigned* smax = (unsigned*)(w + OSMX);
    float* den  = w + ODEN;
    float* deg  = w + ODEG;
    float* aggr = w + OAGG;
    float* hm   = w + OHM;
    float* Xc   = w + OXC;
    float* cf   = w + OCF;
    float* cf1  = w + OCF1;
    float* cf2  = w + OCF2;
    float* eeSc = w + OEESC;
    float* eeBs = w + OEEBS;
    float* mlSc = w + OMLSC;
    float* mlBs = w + OMLBS;

    const long long HS_N = (long long)CB * CS * CSD;
    const long long XC_N = (long long)CN * CD;

    // ---- init ----
    dk_copy_f32<<<(unsigned)((HS_N + 255) / 256), 256, 0, stream>>>(hidden, hs, HS_N);
    dk_copy_f32<<<(unsigned)((XC_N + 255) / 256), 256, 0, stream>>>(Xin, Xc, XC_N);
    dk_fold_bn<<<1, 256, 0, stream>>>(eeb1, eebnw, eebnb, eeSc, eeBs, CD);
    dk_fold_bn<<<4, 256, 0, stream>>>(mb1, mbnw, mbnb, mlSc, mlBs, CK * CD);

    // ---- edge embeddings (shared across GAT layers) ----
    dk_ee_gather<<<CEN, 256, 0, stream>>>(eew1, eeSc, eeBs, eidx, etyp, ntyp, keyE);
    mgemm_go(stream, 0, keyE, eew2, eeb2, 0, nullptr, nullptr, eemb,
             CEN, CD, CD, CD, CD, CD);

    // ---- degree ----
    dk_deg_init<<<(CN + 255) / 256, 256, 0, stream>>>(deg);
    dk_deg_count<<<(CE + 255) / 256, 256, 0, stream>>>(eidx, deg);

    const long long sBH = (long long)CS * CSD;
    const long long sAT = (long long)CNH * CS * CS;

    for (int i = 0; i < CL; i++) {
        // qkv: batched z=0,1,2 -> qb,kb,vb (contiguous in ws)
        mgemm_go(stream, 0, hs, qkv_w + (long long)i * 3 * CSD * CSD,
                 qkv_b + (long long)i * 3 * CSD, CSD, nullptr, nullptr, qb,
                 CB * CS, CSD, CSD, CSD, CSD, CSD,
                 3, 1, 0, 0, (long long)CSD * CSD, 0, 1572864LL, 0);
        // scores = q @ k^T (batched over b,h)
        mgemm_go(stream, 1, qb, kb, nullptr, 0, nullptr, nullptr, attb,
                 CS, CS, CDH, CSD, CSD, CS,
                 CB * CNH, CNH, sBH, CDH, sBH, CDH, sAT, (long long)CS * CS);
        dk_att_softmax<<<CB * CNH * CS, 256, 0, stream>>>(attb, amask);
        // ctx = att @ v
        mgemm_go(stream, 0, attb, vb, nullptr, 0, nullptr, nullptr, ctx,
                 CS, CDH, CS, CS, CSD, CSD,
                 CB * CNH, CNH, sAT, (long long)CS * CS, sBH, CDH, sBH, CDH);
        // out proj + residual, then LN1
        mgemm_go(stream, 2, ctx, aow + (long long)i * CSD * CSD,
                 aob + (long long)i * CSD, 0, nullptr, hs, tmp,
                 CB * CS, CSD, CSD, CSD, CSD, CSD);
        dk_ln_row<<<CB * CS, 256, 0, stream>>>(tmp, ln1w + (long long)i * CSD, ln1b + (long long)i * CSD, atn);
        // ffn
        mgemm_go(stream, 3, atn, f1w + (long long)i * CSD * CFF,
                 f1b + (long long)i * CFF, 0, nullptr, nullptr, inter,
                 CB * CS, CFF, CSD, CSD, CFF, CFF);
        mgemm_go(stream, 2, inter, f2w + (long long)i * CFF * CSD,
                 f2b + (long long)i * CSD, 0, nullptr, atn, tmp,
                 CB * CS, CSD, CFF, CFF, CSD, CSD);
        dk_ln_row<<<CB * CS, 256, 0, stream>>>(tmp, ln2w + (long long)i * CSD, ln2b + (long long)i * CSD, hs);

        if (i >= CL - CK) {
            int g = i - (CL - CK);
            dk_x2_build<<<(CN * 2 * CD + 255) / 256, 256, 0, stream>>>(Xc, nfe, x2);
            mgemm_go(stream, 0, x2, gqw + (long long)g * 2 * CD * CD,
                     gqb + (long long)g * CD, 0, nullptr, nullptr, qryN,
                     CN, CD, 2 * CD, 2 * CD, CD, CD);
            mgemm_go(stream, 0, x2, gkw + (long long)g * 3 * CD * CD,
                     gkb + (long long)g * CD, 0, nullptr, nullptr, keyN,
                     CN, CD, 2 * CD, 2 * CD, CD, CD);
            mgemm_go(stream, 0, x2, gmw + (long long)g * 3 * CD * CD,
                     gmb + (long long)g * CD, 0, nullptr, nullptr, msgN,
                     CN, CD, 2 * CD, 2 * CD, CD, CD);
            mgemm_go(stream, 0, eemb,
                     gkw + (long long)g * 3 * CD * CD + (long long)2 * CD * CD,
                     nullptr, 0, nullptr, nullptr, keyE, CEN, CD, CD, CD, CD, CD);
            mgemm_go(stream, 0, eemb,
                     gmw + (long long)g * 3 * CD * CD + (long long)2 * CD * CD,
                     nullptr, 0, nullptr, nullptr, msgE, CEN, CD, CD, CD, CD, CD);
            hipMemsetAsync(smax, 0, CN * CHC * sizeof(unsigned), stream);
            hipMemsetAsync(den, 0, CN * CHC * sizeof(float), stream);
            hipMemsetAsync(aggr, 0, (size_t)CN * CD * sizeof(float), stream);
            dk_gat_scores<<<(CEN * CHC + 255) / 256, 256, 0, stream>>>(qryN, keyN, keyE, eidx, scrs, smax);
            dk_gat_expsum<<<(CEN * CHC + 255) / 256, 256, 0, stream>>>(smax, eidx, scrs, den);
            dk_gat_aggr<<<CEN, 256, 0, stream>>>(msgN, msgE, scrs, den, deg, eidx, aggr);
            mgemm_go(stream, 4, aggr, mw1 + (long long)g * CD * CD,
                     mlBs + (long long)g * CD, 0, mlSc + (long long)g * CD, nullptr, hm,
                     CN, CD, CD, CD, CD, CD);
            mgemm_go(stream, 3, hm, mw2 + (long long)g * CD * CD,
                     mb2 + (long long)g * CD, 0, nullptr, nullptr, Xc,
                     CN, CD, CD, CD, CD, CD);
            dk_cf_build<<<(CB * (CSD + CD) + 255) / 256, 256, 0, stream>>>(hs, Xc, cf);
            {
                dim3 g1((CIE + 63) / 64, 1, 1);
                dk_gemm64<2><<<g1, 256, 0, stream>>>(cf, iew1, ieb1, cf1,
                        CB, CIE, CSD + CD, CSD + CD, CIE, CIE);
                dim3 g2((CSD + CD + 63) / 64, 1, 1);
                dk_gemm64<0><<<g2, 256, 0, stream>>>(cf1, iew2, ieb2, cf2,
                        CB, CSD + CD, CIE, CIE, CSD + CD, CSD + CD);
            }
            dk_cf_scatter<<<(CB * (CSD + CD) + 255) / 256, 256, 0, stream>>>(cf2, hs, Xc);
        }
    }

    dk_copy_f32<<<(unsigned)((XC_N + 255) / 256), 256, 0, stream>>>(Xc, XcOut, XC_N);
}

// Round 3
// 7266.631 us; speedup vs baseline: 3.4162x; 1.2638x over previous
//
#include <hip/hip_runtime.h>
#include <math.h>

// ---------------- problem constants ----------------
namespace {
constexpr int CB = 8, CS = 256, CSD = 768, CL = 12, CNH = 12, CDH = 64, CFF = 3072;
constexpr int CK = 5, CD = 200, CHC = 4, CDPH = 50, CNNT = 4, CNET = 38;
constexpr int CNN = 200, CN = 1600, CE = 50000, CEN = 51600, CIE = 200;

// workspace offsets (floats)
constexpr long long OQ    = 0;
constexpr long long OK2   = OQ    + 1572864;   // k
constexpr long long OV2   = OK2   + 1572864;   // v
constexpr long long OATT  = OV2   + 1572864;   // att [96,256,256]
constexpr long long OCTX  = OATT  + 6291456;
constexpr long long OTMP  = OCTX  + 1572864;
constexpr long long OATN  = OTMP  + 1572864;
constexpr long long OINT  = OATN  + 1572864;   // ffn intermediate [2048,3072]
constexpr long long OEE   = OINT  + 6291456;   // edge_emb [51600,200]
constexpr long long OKE   = OEE   + 10320000;  // keyE (also h_ee scratch)
constexpr long long OME   = OKE   + 10320000;  // msgE
constexpr long long OX2   = OME   + 10320000;  // x2 [1600,400]
constexpr long long OKN   = OX2   + 640000;    // keyN
constexpr long long OMN   = OKN   + 320000;    // msgN
constexpr long long OQN   = OMN   + 320000;    // qryN
constexpr long long OSC   = OQN   + 320000;    // scores [51600,4]
constexpr long long OSMX  = OSC   + 206400;    // smax (uint enc)
constexpr long long ODEN  = OSMX  + 6400;
constexpr long long ODEG  = ODEN  + 6400;
constexpr long long OAGG  = ODEG  + 1600;      // aggr [1600,200]
constexpr long long OHM   = OAGG  + 320000;
constexpr long long OXC   = OHM   + 320000;    // Xc working copy
constexpr long long OCF   = OXC   + 320000;    // cf [8,968]
constexpr long long OCF1  = OCF   + 7744;
constexpr long long OCF2  = OCF1  + 1600;
constexpr long long OEESC = OCF2  + 7744;      // ee folded bn scale
constexpr long long OEEBS = OEESC + 200;
constexpr long long OMLSC = OEEBS + 200;       // gat mlp folded (5*200)
constexpr long long OMLBS = OMLSC + 1000;
}

typedef __attribute__((ext_vector_type(8))) short bh8;
typedef __attribute__((ext_vector_type(4))) float fx4;

// ---------------- helpers ----------------
__device__ inline unsigned dk_fenc(float f) {
    unsigned u = __float_as_uint(f);
    return (u & 0x80000000u) ? ~u : (u | 0x80000000u);
}
__device__ inline float dk_fdec(unsigned u) {
    return (u & 0x80000000u) ? __uint_as_float(u & 0x7fffffffu) : __uint_as_float(~u);
}
__device__ inline float dk_gelu(float v) {
    return 0.5f * v * (1.0f + erff(v * 0.70710678118654752f));
}
__device__ inline short dk_f2bf(float f) {
    unsigned u = __float_as_uint(f);
    unsigned r = (u + 0x7fffu + ((u >> 16) & 1u)) >> 16;
    return (short)r;
}

// ---------------- bf16 MFMA GEMM: 128x64 tile, BK=32, double-buffered LDS ----
// C = act( A@B * scale[n] + bias[z][n] + R ), batched z = zo*innerB + zi.
// A fp32 [M,K] (lda), B fp32: TRANSB ? [N,K] (ldb) : [K,N] (ldb).
template<bool TRANSB, int ACT, bool HAS_SCALE, bool HAS_RES>
__global__ __launch_bounds__(256)
void dk_mgemm(const float* __restrict__ A, const float* __restrict__ Bm,
              const float* __restrict__ bias, long long sBias,
              const float* __restrict__ scale, const float* __restrict__ Rm,
              float* __restrict__ C,
              int M, int N, int K, int lda, int ldb, int ldc,
              int innerB, long long sAo, long long sAi, long long sBo, long long sBi,
              long long sCo, long long sCi)
{
    int z = blockIdx.z;
    int zo = z / innerB, zi = z - zo * innerB;
    A  += (long long)zo * sAo + (long long)zi * sAi;
    Bm += (long long)zo * sBo + (long long)zi * sBi;
    const float* biasp = bias ? (bias + (long long)z * sBias) : nullptr;
    long long coff = (long long)zo * sCo + (long long)zi * sCi;

    // double-buffered: A 128x32 bf16 (8KB), B 64x32 bf16 (4KB) per buffer
    __shared__ __align__(16) short As[2][128 * 32];
    __shared__ __align__(16) short Bs[2][64 * 32];

    int tid = threadIdx.x;
    int m0 = blockIdx.y * 128, n0 = blockIdx.x * 64;

    int l = tid & 63, w = tid >> 6;
    int wm = (w >> 1) * 64, wn = (w & 1) * 32;
    int lr = l & 15, lkB = (l >> 4) * 16;   // byte offset of k-slice within 64B row

    fx4 acc[4][2] = {};

    // staging registers
    bh8 ra0, ra1, rb0;

    int arow = tid >> 2;                 // 0..63 (A rows, +64 for second half)
    int akcB = (tid & 3) * 16;           // byte offset within 64B LDS row
    int bn = tid & 63, bkI = tid >> 6;   // B non-trans mapping

    // row-major [rows, K] loader (A, and B when TRANSB)
    auto loadRowK = [&](const float* P, int r0, int r, int kk, int Rows, int ld) -> bh8 {
        bh8 s;
        if ((r0 + r) < Rows && kk + 8 <= K) {
            const float4* p = reinterpret_cast<const float4*>(P + (long long)(r0 + r) * ld + kk);
            float4 a = p[0], b = p[1];
            s[0] = dk_f2bf(a.x); s[1] = dk_f2bf(a.y); s[2] = dk_f2bf(a.z); s[3] = dk_f2bf(a.w);
            s[4] = dk_f2bf(b.x); s[5] = dk_f2bf(b.y); s[6] = dk_f2bf(b.z); s[7] = dk_f2bf(b.w);
        } else {
#pragma unroll
            for (int j = 0; j < 8; j++) s[j] = 0;
        }
        return s;
    };
    // B non-trans: [K, N], strided along k
    auto loadKN = [&](int n, int kk) -> bh8 {
        bh8 s;
        if ((n0 + n) < N && kk + 8 <= K) {
            const float* p = Bm + (long long)kk * ldb + (n0 + n);
#pragma unroll
            for (int j = 0; j < 8; j++) s[j] = dk_f2bf(p[(long long)j * ldb]);
        } else {
#pragma unroll
            for (int j = 0; j < 8; j++) s[j] = 0;
        }
        return s;
    };

    auto gload = [&](int k0) {
        int kc = k0 + (tid & 3) * 8;
        ra0 = loadRowK(A, m0, arow, kc, M, lda);
        ra1 = loadRowK(A, m0, arow + 64, kc, M, lda);
        if (TRANSB) rb0 = loadRowK(Bm, n0, arow, kc, N, ldb);
        else        rb0 = loadKN(bn, k0 + bkI * 8);
    };
    auto swz = [](int row) { return ((row >> 1) & 3) << 4; };
    auto dswrite = [&](int buf) {
        *(bh8*)((char*)As[buf] + arow * 64 + (akcB ^ swz(arow))) = ra0;
        *(bh8*)((char*)As[buf] + (arow + 64) * 64 + (akcB ^ swz(arow + 64))) = ra1;
        if (TRANSB)
            *(bh8*)((char*)Bs[buf] + arow * 64 + (akcB ^ swz(arow))) = rb0;
        else
            *(bh8*)((char*)Bs[buf] + bn * 64 + ((bkI * 16) ^ swz(bn))) = rb0;
    };

    int NT = (K + 31) / 32;
    // prologue: tile 0 into buf 0 (one exposed latency per block)
    gload(0);
    dswrite(0);
    __syncthreads();
    int cur = 0;
    for (int t = 0; t < NT; ++t) {
        bool more = (t + 1 < NT);
        if (more) gload((t + 1) * 32);   // issue next tile's loads first

        bh8 af[4], bf[2];
#pragma unroll
        for (int mi = 0; mi < 4; mi++) {
            int ra = wm + mi * 16 + lr;
            af[mi] = *(const bh8*)((const char*)As[cur] + ra * 64 + (lkB ^ swz(ra)));
        }
#pragma unroll
        for (int ni = 0; ni < 2; ni++) {
            int rb = wn + ni * 16 + lr;
            bf[ni] = *(const bh8*)((const char*)Bs[cur] + rb * 64 + (lkB ^ swz(rb)));
        }
#pragma unroll
        for (int mi = 0; mi < 4; mi++)
#pragma unroll
            for (int ni = 0; ni < 2; ni++)
                acc[mi][ni] = __builtin_amdgcn_mfma_f32_16x16x32_bf16(af[mi], bf[ni], acc[mi][ni], 0, 0, 0);

        if (more) {
            dswrite(cur ^ 1);     // vmcnt wait largely covered by compute above
            __syncthreads();      // single barrier per K-step
            cur ^= 1;
        }
    }

    // ---- epilogue ----
    const float* R = HAS_RES ? (Rm + coff) : nullptr;
    float* Cc = C + coff;
#pragma unroll
    for (int ni = 0; ni < 2; ni++) {
        int nn = n0 + wn + ni * 16 + lr;
        if (nn >= N) continue;
        float sc = HAS_SCALE ? scale[nn] : 1.0f;
        float bi = biasp ? biasp[nn] : 0.0f;
#pragma unroll
        for (int mi = 0; mi < 4; mi++) {
#pragma unroll
            for (int r = 0; r < 4; r++) {
                int mm = m0 + wm + mi * 16 + (l >> 4) * 4 + r;
                if (mm >= M) continue;
                float v = acc[mi][ni][r];
                if (HAS_SCALE) v *= sc;
                v += bi;
                if (HAS_RES) v += R[(long long)mm * ldc + nn];
                if (ACT == 1) v = fmaxf(v, 0.f);
                if (ACT == 2) v = dk_gelu(v);
                Cc[(long long)mm * ldc + nn] = v;
            }
        }
    }
}

// ---------------- fp32 fallback GEMM (tiny shapes) ----------------
template<int ACT>
__global__ __launch_bounds__(256)
void dk_gemm64(const float* __restrict__ A, const float* __restrict__ Bm,
               const float* __restrict__ bias, float* __restrict__ C,
               int M, int N, int K, int lda, int ldb, int ldc)
{
    __shared__ float As[16][65];
    __shared__ float Bs[16][65];
    int tid = threadIdx.x;
    int tx = tid & 15, ty = tid >> 4;
    int m0 = blockIdx.y * 64, n0 = blockIdx.x * 64;
    float acc[4][4] = {};
    for (int k0 = 0; k0 < K; k0 += 16) {
#pragma unroll
        for (int i = 0; i < 4; i++) {
            int idx = tid + i * 256;
            int r = idx >> 4, c = idx & 15;
            int mm = m0 + r, kk = k0 + c;
            As[c][r] = (mm < M && kk < K) ? A[(long long)mm * lda + kk] : 0.f;
        }
#pragma unroll
        for (int i = 0; i < 4; i++) {
            int idx = tid + i * 256;
            int n = idx & 63, kk = idx >> 6;
            int nn = n0 + n, kx = k0 + kk;
            Bs[kk][n] = (nn < N && kx < K) ? Bm[(long long)kx * ldb + nn] : 0.f;
        }
        __syncthreads();
#pragma unroll
        for (int kk = 0; kk < 16; kk++) {
            float a[4], b[4];
#pragma unroll
            for (int i = 0; i < 4; i++) a[i] = As[kk][ty * 4 + i];
#pragma unroll
            for (int j = 0; j < 4; j++) b[j] = Bs[kk][tx * 4 + j];
#pragma unroll
            for (int i = 0; i < 4; i++)
#pragma unroll
                for (int j = 0; j < 4; j++) acc[i][j] += a[i] * b[j];
        }
        __syncthreads();
    }
#pragma unroll
    for (int i = 0; i < 4; i++) {
        int mm = m0 + ty * 4 + i;
        if (mm >= M) continue;
#pragma unroll
        for (int j = 0; j < 4; j++) {
            int nn = n0 + tx * 4 + j;
            if (nn >= N) continue;
            float v = acc[i][j];
            if (bias) v += bias[nn];
            if (ACT == 2) v = dk_gelu(v);
            C[(long long)mm * ldc + nn] = v;
        }
    }
}

// ---------------- attention softmax (row = one (b,h,q)) ----------------
__global__ __launch_bounds__(256)
void dk_att_softmax(float* __restrict__ att, const float* __restrict__ mask)
{
    int row = blockIdx.x;
    int b = row / (CNH * CS);
    int tid = threadIdx.x;
    float x = att[(long long)row * CS + tid] * 0.125f + mask[b * CS + tid];
    __shared__ float red[256];
    red[tid] = x; __syncthreads();
    for (int s = 128; s; s >>= 1) { if (tid < s) red[tid] = fmaxf(red[tid], red[tid + s]); __syncthreads(); }
    float mx = red[0]; __syncthreads();
    float e = expf(x - mx);
    red[tid] = e; __syncthreads();
    for (int s = 128; s; s >>= 1) { if (tid < s) red[tid] += red[tid + s]; __syncthreads(); }
    float sum = red[0];
    att[(long long)row * CS + tid] = e / sum;
}

// ---------------- layernorm over 768 ----------------
__global__ __launch_bounds__(256)
void dk_ln_row(const float* __restrict__ in, const float* __restrict__ w,
               const float* __restrict__ b, float* __restrict__ out)
{
    int row = blockIdx.x, tid = threadIdx.x;
    const float* ip = in + (long long)row * CSD;
    float xv[3];
    float s = 0.f;
#pragma unroll
    for (int t = 0; t < 3; t++) { xv[t] = ip[tid + t * 256]; s += xv[t]; }
    __shared__ float red[256];
    red[tid] = s; __syncthreads();
    for (int st = 128; st; st >>= 1) { if (tid < st) red[tid] += red[tid + st]; __syncthreads(); }
    float mean = red[0] * (1.f / 768.f); __syncthreads();
    float v = 0.f;
#pragma unroll
    for (int t = 0; t < 3; t++) { float d = xv[t] - mean; v += d * d; }
    red[tid] = v; __syncthreads();
    for (int st = 128; st; st >>= 1) { if (tid < st) red[tid] += red[tid + st]; __syncthreads(); }
    float var = red[0] * (1.f / 768.f);
    float rs = 1.0f / sqrtf(var + 1e-12f);
    float* op = out + (long long)row * CSD;
#pragma unroll
    for (int t = 0; t < 3; t++) {
        int c = tid + t * 256;
        op[c] = (xv[t] - mean) * rs * w[c] + b[c];
    }
}

// ---------------- small utility kernels ----------------
__global__ void dk_copy_f32(const float* __restrict__ a, float* __restrict__ o, long long n)
{
    long long i = (long long)blockIdx.x * 256 + threadIdx.x;
    if (i < n) o[i] = a[i];
}

__global__ void dk_fold_bn(const float* __restrict__ b1, const float* __restrict__ bw,
                           const float* __restrict__ bb, float* __restrict__ sc,
                           float* __restrict__ bs, int n)
{
    int i = blockIdx.x * 256 + threadIdx.x;
    if (i >= n) return;
    float c = 1.0f / sqrtf(1.0f + 1e-5f);
    sc[i] = c * bw[i];
    bs[i] = b1[i] * c * bw[i] + bb[i];
}

__global__ __launch_bounds__(256)
void dk_ee_gather(const float* __restrict__ w1, const float* __restrict__ sc,
                  const float* __restrict__ bs, const int* __restrict__ eidx,
                  const int* __restrict__ etyp, const int* __restrict__ ntyp,
                  float* __restrict__ out)
{
    int e = blockIdx.x, d = threadIdx.x;
    if (d >= CD) return;
    int t0, s, t;
    if (e < CE) { t0 = etyp[e]; s = eidx[e]; t = eidx[CE + e]; }
    else        { t0 = CNET; s = t = e - CE; }
    int h0 = ntyp[s], t1 = ntyp[t];
    float v = w1[t0 * CD + d] + w1[(CNET + 1 + h0) * CD + d] + w1[(CNET + 1 + CNNT + t1) * CD + d];
    v = v * sc[d] + bs[d];
    out[(long long)e * CD + d] = fmaxf(v, 0.f);
}

__global__ void dk_deg_init(float* __restrict__ deg)
{
    int i = blockIdx.x * 256 + threadIdx.x;
    if (i < CN) deg[i] = 1.0f;
}
__global__ void dk_deg_count(const int* __restrict__ eidx, float* __restrict__ deg)
{
    int e = blockIdx.x * 256 + threadIdx.x;
    if (e < CE) atomicAdd(&deg[eidx[e]], 1.0f);
}

__global__ void dk_x2_build(const float* __restrict__ Xc, const float* __restrict__ nfe,
                            float* __restrict__ x2)
{
    int i = blockIdx.x * 256 + threadIdx.x;
    if (i >= CN * 2 * CD) return;
    int n = i / (2 * CD), d = i % (2 * CD);
    x2[i] = (d < CD) ? Xc[(long long)n * CD + d] : nfe[(long long)n * CD + (d - CD)];
}

__global__ __launch_bounds__(256)
void dk_gat_scores(const float* __restrict__ qryN, const float* __restrict__ keyN,
                   const float* __restrict__ keyE, const int* __restrict__ eidx,
                   float* __restrict__ scores, unsigned* __restrict__ smax)
{
    long long id = (long long)blockIdx.x * 256 + threadIdx.x;
    if (id >= (long long)CEN * CHC) return;
    int e = (int)(id >> 2), h = (int)(id & 3);
    int s, t;
    if (e < CE) { s = eidx[e]; t = eidx[CE + e]; } else { s = t = e - CE; }
    const float* qp = qryN + (long long)s * CD + h * CDPH;
    const float* kp = keyN + (long long)t * CD + h * CDPH;
    const float* ke = keyE + (long long)e * CD + h * CDPH;
    float acc = 0.f;
#pragma unroll 10
    for (int d = 0; d < CDPH; d++) acc += qp[d] * (kp[d] + ke[d]);
    acc *= 0.14142135623730950488f;
    scores[id] = acc;
    atomicMax(&smax[s * CHC + h], dk_fenc(acc));
}

__global__ __launch_bounds__(256)
void dk_gat_expsum(const unsigned* __restrict__ smax, const int* __restrict__ eidx,
                   float* __restrict__ scores, float* __restrict__ den)
{
    long long id = (long long)blockIdx.x * 256 + threadIdx.x;
    if (id >= (long long)CEN * CHC) return;
    int e = (int)(id >> 2), h = (int)(id & 3);
    int s;
    if (e < CE) s = eidx[e]; else s = e - CE;
    float ex = expf(scores[id] - dk_fdec(smax[s * CHC + h]));
    scores[id] = ex;
    atomicAdd(&den[s * CHC + h], ex);
}

__global__ __launch_bounds__(256)
void dk_gat_aggr(const float* __restrict__ msgN, const float* __restrict__ msgE,
                 const float* __restrict__ scores, const float* __restrict__ den,
                 const float* __restrict__ deg, const int* __restrict__ eidx,
                 float* __restrict__ aggr)
{
    int e = blockIdx.x, d = threadIdx.x;
    if (d >= CD) return;
    int s, t;
    if (e < CE) { s = eidx[e]; t = eidx[CE + e]; } else { s = t = e - CE; }
    int h = d / CDPH;
    float alpha = scores[(long long)e * CHC + h] / (den[s * CHC + h] + 1e-16f) * deg[s];
    float v = (msgN[(long long)s * CD + d] + msgE[(long long)e * CD + d]) * alpha;
    atomicAdd(&aggr[(long long)t * CD + d], v);
}

__global__ void dk_cf_build(const float* __restrict__ hs, const float* __restrict__ Xc,
                            float* __restrict__ cf)
{
    int i = blockIdx.x * 256 + threadIdx.x;
    if (i >= CB * (CSD + CD)) return;
    int b = i / (CSD + CD), c = i % (CSD + CD);
    cf[i] = (c < CSD) ? hs[(long long)b * CS * CSD + c]
                      : Xc[(long long)b * CNN * CD + (c - CSD)];
}

__global__ void dk_cf_scatter(const float* __restrict__ cf2, float* __restrict__ hs,
                              float* __restrict__ Xc)
{
    int i = blockIdx.x * 256 + threadIdx.x;
    if (i >= CB * (CSD + CD)) return;
    int b = i / (CSD + CD), c = i % (CSD + CD);
    float v = cf2[i];
    if (c < CSD) hs[(long long)b * CS * CSD + c] = v;
    else         Xc[(long long)b * CNN * CD + (c - CSD)] = v;
}

// ---------------- host-side MFMA GEMM dispatch ----------------
// mode: 0=plain, 1=transb, 2=res, 3=gelu, 4=relu+scale
static void mgemm_go(hipStream_t st, int mode,
                     const float* A, const float* B, const float* bias, long long sBias,
                     const float* scale, const float* R, float* C,
                     int M, int N, int K, int lda, int ldb, int ldc,
                     int batches = 1, int innerB = 1,
                     long long sAo = 0, long long sAi = 0, long long sBo = 0, long long sBi = 0,
                     long long sCo = 0, long long sCi = 0)
{
    dim3 grid((N + 63) / 64, (M + 127) / 128, batches), blk(256);
    switch (mode) {
    case 0: dk_mgemm<false, 0, false, false><<<grid, blk, 0, st>>>(A, B, bias, sBias, scale, R, C, M, N, K, lda, ldb, ldc, innerB, sAo, sAi, sBo, sBi, sCo, sCi); break;
    case 1: dk_mgemm<true,  0, false, false><<<grid, blk, 0, st>>>(A, B, bias, sBias, scale, R, C, M, N, K, lda, ldb, ldc, innerB, sAo, sAi, sBo, sBi, sCo, sCi); break;
    case 2: dk_mgemm<false, 0, false, true ><<<grid, blk, 0, st>>>(A, B, bias, sBias, scale, R, C, M, N, K, lda, ldb, ldc, innerB, sAo, sAi, sBo, sBi, sCo, sCi); break;
    case 3: dk_mgemm<false, 2, false, false><<<grid, blk, 0, st>>>(A, B, bias, sBias, scale, R, C, M, N, K, lda, ldb, ldc, innerB, sAo, sAi, sBo, sBi, sCo, sCi); break;
    case 4: dk_mgemm<false, 1, true,  false><<<grid, blk, 0, st>>>(A, B, bias, sBias, scale, R, C, M, N, K, lda, ldb, ldc, innerB, sAo, sAi, sBo, sBi, sCo, sCi); break;
    }
}

// ---------------- launch ----------------
extern "C" void kernel_launch(void* const* d_in, const int* in_sizes, int n_in,
                              void* d_out, int out_size, void* d_ws, size_t ws_size,
                              hipStream_t stream)
{
    const float* hidden = (const float*)d_in[0];
    const float* amask  = (const float*)d_in[1];
    const float* Xin    = (const float*)d_in[2];
    const float* nfe    = (const float*)d_in[3];
    const float* qkv_w  = (const float*)d_in[4];
    const float* qkv_b  = (const float*)d_in[5];
    const float* aow    = (const float*)d_in[6];
    const float* aob    = (const float*)d_in[7];
    const float* ln1w   = (const float*)d_in[8];
    const float* ln1b   = (const float*)d_in[9];
    const float* f1w    = (const float*)d_in[10];
    const float* f1b    = (const float*)d_in[11];
    const float* f2w    = (const float*)d_in[12];
    const float* f2b    = (const float*)d_in[13];
    const float* ln2w   = (const float*)d_in[14];
    const float* ln2b   = (const float*)d_in[15];
    const float* eew1   = (const float*)d_in[16];
    const float* eeb1   = (const float*)d_in[17];
    const float* eebnw  = (const float*)d_in[18];
    const float* eebnb  = (const float*)d_in[19];
    const float* eew2   = (const float*)d_in[20];
    const float* eeb2   = (const float*)d_in[21];
    const float* gkw    = (const float*)d_in[22];
    const float* gkb    = (const float*)d_in[23];
    const float* gmw    = (const float*)d_in[24];
    const float* gmb    = (const float*)d_in[25];
    const float* gqw    = (const float*)d_in[26];
    const float* gqb    = (const float*)d_in[27];
    const float* mw1    = (const float*)d_in[28];
    const float* mb1    = (const float*)d_in[29];
    const float* mbnw   = (const float*)d_in[30];
    const float* mbnb   = (const float*)d_in[31];
    const float* mw2    = (const float*)d_in[32];
    const float* mb2    = (const float*)d_in[33];
    const float* iew1   = (const float*)d_in[34];
    const float* ieb1   = (const float*)d_in[35];
    const float* iew2   = (const float*)d_in[36];
    const float* ieb2   = (const float*)d_in[37];
    const int*   eidx   = (const int*)d_in[38];
    const int*   etyp   = (const int*)d_in[39];
    const int*   ntyp   = (const int*)d_in[40];

    float* hs    = (float*)d_out;
    float* XcOut = hs + (long long)CB * CS * CSD;

    float* w = (float*)d_ws;
    float* qb   = w + OQ;
    float* kb   = w + OK2;
    float* vb   = w + OV2;
    float* attb = w + OATT;
    float* ctx  = w + OCTX;
    float* tmp  = w + OTMP;
    float* atn  = w + OATN;
    float* inter= w + OINT;
    float* eemb = w + OEE;
    float* keyE = w + OKE;
    float* msgE = w + OME;
    float* x2   = w + OX2;
    float* keyN = w + OKN;
    float* msgN = w + OMN;
    float* qryN = w + OQN;
    float* scrs = w + OSC;
    unsigned* smax = (unsigned*)(w + OSMX);
    float* den  = w + ODEN;
    float* deg  = w + ODEG;
    float* aggr = w + OAGG;
    float* hm   = w + OHM;
    float* Xc   = w + OXC;
    float* cf   = w + OCF;
    float* cf1  = w + OCF1;
    float* cf2  = w + OCF2;
    float* eeSc = w + OEESC;
    float* eeBs = w + OEEBS;
    float* mlSc = w + OMLSC;
    float* mlBs = w + OMLBS;

    const long long HS_N = (long long)CB * CS * CSD;
    const long long XC_N = (long long)CN * CD;

    // ---- init ----
    dk_copy_f32<<<(unsigned)((HS_N + 255) / 256), 256, 0, stream>>>(hidden, hs, HS_N);
    dk_copy_f32<<<(unsigned)((XC_N + 255) / 256), 256, 0, stream>>>(Xin, Xc, XC_N);
    dk_fold_bn<<<1, 256, 0, stream>>>(eeb1, eebnw, eebnb, eeSc, eeBs, CD);
    dk_fold_bn<<<4, 256, 0, stream>>>(mb1, mbnw, mbnb, mlSc, mlBs, CK * CD);

    // ---- edge embeddings (shared across GAT layers) ----
    dk_ee_gather<<<CEN, 256, 0, stream>>>(eew1, eeSc, eeBs, eidx, etyp, ntyp, keyE);
    mgemm_go(stream, 0, keyE, eew2, eeb2, 0, nullptr, nullptr, eemb,
             CEN, CD, CD, CD, CD, CD);

    // ---- degree ----
    dk_deg_init<<<(CN + 255) / 256, 256, 0, stream>>>(deg);
    dk_deg_count<<<(CE + 255) / 256, 256, 0, stream>>>(eidx, deg);

    const long long sBH = (long long)CS * CSD;
    const long long sAT = (long long)CNH * CS * CS;

    for (int i = 0; i < CL; i++) {
        // qkv: batched z=0,1,2 -> qb,kb,vb (contiguous in ws)
        mgemm_go(stream, 0, hs, qkv_w + (long long)i * 3 * CSD * CSD,
                 qkv_b + (long long)i * 3 * CSD, CSD, nullptr, nullptr, qb,
                 CB * CS, CSD, CSD, CSD, CSD, CSD,
                 3, 1, 0, 0, (long long)CSD * CSD, 0, 1572864LL, 0);
        // scores = q @ k^T (batched over b,h)
        mgemm_go(stream, 1, qb, kb, nullptr, 0, nullptr, nullptr, attb,
                 CS, CS, CDH, CSD, CSD, CS,
                 CB * CNH, CNH, sBH, CDH, sBH, CDH, sAT, (long long)CS * CS);
        dk_att_softmax<<<CB * CNH * CS, 256, 0, stream>>>(attb, amask);
        // ctx = att @ v
        mgemm_go(stream, 0, attb, vb, nullptr, 0, nullptr, nullptr, ctx,
                 CS, CDH, CS, CS, CSD, CSD,
                 CB * CNH, CNH, sAT, (long long)CS * CS, sBH, CDH, sBH, CDH);
        // out proj + residual, then LN1
        mgemm_go(stream, 2, ctx, aow + (long long)i * CSD * CSD,
                 aob + (long long)i * CSD, 0, nullptr, hs, tmp,
                 CB * CS, CSD, CSD, CSD, CSD, CSD);
        dk_ln_row<<<CB * CS, 256, 0, stream>>>(tmp, ln1w + (long long)i * CSD, ln1b + (long long)i * CSD, atn);
        // ffn
        mgemm_go(stream, 3, atn, f1w + (long long)i * CSD * CFF,
                 f1b + (long long)i * CFF, 0, nullptr, nullptr, inter,
                 CB * CS, CFF, CSD, CSD, CFF, CFF);
        mgemm_go(stream, 2, inter, f2w + (long long)i * CFF * CSD,
                 f2b + (long long)i * CSD, 0, nullptr, atn, tmp,
                 CB * CS, CSD, CFF, CFF, CSD, CSD);
        dk_ln_row<<<CB * CS, 256, 0, stream>>>(tmp, ln2w + (long long)i * CSD, ln2b + (long long)i * CSD, hs);

        if (i >= CL - CK) {
            int g = i - (CL - CK);
            dk_x2_build<<<(CN * 2 * CD + 255) / 256, 256, 0, stream>>>(Xc, nfe, x2);
            mgemm_go(stream, 0, x2, gqw + (long long)g * 2 * CD * CD,
                     gqb + (long long)g * CD, 0, nullptr, nullptr, qryN,
                     CN, CD, 2 * CD, 2 * CD, CD, CD);
            mgemm_go(stream, 0, x2, gkw + (long long)g * 3 * CD * CD,
                     gkb + (long long)g * CD, 0, nullptr, nullptr, keyN,
                     CN, CD, 2 * CD, 2 * CD, CD, CD);
            mgemm_go(stream, 0, x2, gmw + (long long)g * 3 * CD * CD,
                     gmb + (long long)g * CD, 0, nullptr, nullptr, msgN,
                     CN, CD, 2 * CD, 2 * CD, CD, CD);
            mgemm_go(stream, 0, eemb,
                     gkw + (long long)g * 3 * CD * CD + (long long)2 * CD * CD,
                     nullptr, 0, nullptr, nullptr, keyE, CEN, CD, CD, CD, CD, CD);
            mgemm_go(stream, 0, eemb,
                     gmw + (long long)g * 3 * CD * CD + (long long)2 * CD * CD,
                     nullptr, 0, nullptr, nullptr, msgE, CEN, CD, CD, CD, CD, CD);
            hipMemsetAsync(smax, 0, CN * CHC * sizeof(unsigned), stream);
            hipMemsetAsync(den, 0, CN * CHC * sizeof(float), stream);
            hipMemsetAsync(aggr, 0, (size_t)CN * CD * sizeof(float), stream);
            dk_gat_scores<<<(CEN * CHC + 255) / 256, 256, 0, stream>>>(qryN, keyN, keyE, eidx, scrs, smax);
            dk_gat_expsum<<<(CEN * CHC + 255) / 256, 256, 0, stream>>>(smax, eidx, scrs, den);
            dk_gat_aggr<<<CEN, 256, 0, stream>>>(msgN, msgE, scrs, den, deg, eidx, aggr);
            mgemm_go(stream, 4, aggr, mw1 + (long long)g * CD * CD,
                     mlBs + (long long)g * CD, 0, mlSc + (long long)g * CD, nullptr, hm,
                     CN, CD, CD, CD, CD, CD);
            mgemm_go(stream, 3, hm, mw2 + (long long)g * CD * CD,
                     mb2 + (long long)g * CD, 0, nullptr, nullptr, Xc,
                     CN, CD, CD, CD, CD, CD);
            dk_cf_build<<<(CB * (CSD + CD) + 255) / 256, 256, 0, stream>>>(hs, Xc, cf);
            {
                dim3 g1((CIE + 63) / 64, 1, 1);
                dk_gemm64<2><<<g1, 256, 0, stream>>>(cf, iew1, ieb1, cf1,
                        CB, CIE, CSD + CD, CSD + CD, CIE, CIE);
                dim3 g2((CSD + CD + 63) / 64, 1, 1);
                dk_gemm64<0><<<g2, 256, 0, stream>>>(cf1, iew2, ieb2, cf2,
                        CB, CSD + CD, CIE, CIE, CSD + CD, CSD + CD);
            }
            dk_cf_scatter<<<(CB * (CSD + CD) + 255) / 256, 256, 0, stream>>>(cf2, hs, Xc);
        }
    }

    dk_copy_f32<<<(unsigned)((XC_N + 255) / 256), 256, 0, stream>>>(Xc, XcOut, XC_N);
}

// Round 4
// 6504.823 us; speedup vs baseline: 3.8163x; 1.1171x over previous
//
#include <hip/hip_runtime.h>
#include <math.h>

// ---------------- problem constants ----------------
namespace {
constexpr int CB = 8, CS = 256, CSD = 768, CL = 12, CNH = 12, CDH = 64, CFF = 3072;
constexpr int CK = 5, CD = 200, CHC = 4, CDPH = 50, CNNT = 4, CNET = 38;
constexpr int CNN = 200, CN = 1600, CE = 50000, CEN = 51600, CIE = 200;

// workspace offsets (floats)
constexpr long long OQ    = 0;
constexpr long long OK2   = OQ    + 1572864;   // k
constexpr long long OV2   = OK2   + 1572864;   // v
constexpr long long OATT  = OV2   + 1572864;   // att [96,256,256]
constexpr long long OCTX  = OATT  + 6291456;
constexpr long long OTMP  = OCTX  + 1572864;
constexpr long long OATN  = OTMP  + 1572864;
constexpr long long OINT  = OATN  + 1572864;   // ffn intermediate [2048,3072]
constexpr long long OEE   = OINT  + 6291456;   // edge_emb [51600,200]
constexpr long long OKE   = OEE   + 10320000;  // keyE (also h_ee scratch)
constexpr long long OME   = OKE   + 10320000;  // msgE
constexpr long long OX2   = OME   + 10320000;  // x2 [1600,400]
constexpr long long OKN   = OX2   + 640000;    // keyN
constexpr long long OMN   = OKN   + 320000;    // msgN
constexpr long long OQN   = OMN   + 320000;    // qryN
constexpr long long OSC   = OQN   + 320000;    // scores [51600,4]
constexpr long long OSMX  = OSC   + 206400;    // smax (uint enc)
constexpr long long ODEN  = OSMX  + 6400;
constexpr long long ODEG  = ODEN  + 6400;
constexpr long long OAGG  = ODEG  + 1600;      // aggr [1600,200]
constexpr long long OHM   = OAGG  + 320000;
constexpr long long OXC   = OHM   + 320000;    // Xc working copy
constexpr long long OCF1  = OXC   + 320000;    // cf1 [8,200]
constexpr long long OCF2  = OCF1  + 1600;      // cf2 [8,968]
constexpr long long OEESC = OCF2  + 7744;      // ee folded bn scale
constexpr long long OEEBS = OEESC + 200;
constexpr long long OMLSC = OEEBS + 200;       // gat mlp folded (5*200)
constexpr long long OMLBS = OMLSC + 1000;
}

typedef __attribute__((ext_vector_type(8))) short bh8;
typedef __attribute__((ext_vector_type(4))) float fx4;

// ---------------- helpers ----------------
__device__ inline unsigned dk_fenc(float f) {
    unsigned u = __float_as_uint(f);
    return (u & 0x80000000u) ? ~u : (u | 0x80000000u);
}
__device__ inline float dk_fdec(unsigned u) {
    return (u & 0x80000000u) ? __uint_as_float(u & 0x7fffffffu) : __uint_as_float(~u);
}
__device__ inline float dk_gelu(float v) {
    return 0.5f * v * (1.0f + erff(v * 0.70710678118654752f));
}
__device__ inline short dk_f2bf(float f) {
    unsigned u = __float_as_uint(f);
    unsigned r = (u + 0x7fffu + ((u >> 16) & 1u)) >> 16;
    return (short)r;
}

// ---------------- bf16 MFMA GEMM: 128x64 tile, BK=32, double-buffered LDS ----
// C = act( A@B * scale[n] + bias[z][n] + R ), batched z = zo*innerB + zi.
// A fp32 [M,K] (lda), B fp32: TRANSB ? [N,K] (ldb) : [K,N] (ldb).
template<bool TRANSB, int ACT, bool HAS_SCALE, bool HAS_RES>
__global__ __launch_bounds__(256)
void dk_mgemm(const float* __restrict__ A, const float* __restrict__ Bm,
              const float* __restrict__ bias, long long sBias,
              const float* __restrict__ scale, const float* __restrict__ Rm,
              float* __restrict__ C,
              int M, int N, int K, int lda, int ldb, int ldc,
              int innerB, long long sAo, long long sAi, long long sBo, long long sBi,
              long long sCo, long long sCi)
{
    int z = blockIdx.z;
    int zo = z / innerB, zi = z - zo * innerB;
    A  += (long long)zo * sAo + (long long)zi * sAi;
    Bm += (long long)zo * sBo + (long long)zi * sBi;
    const float* biasp = bias ? (bias + (long long)z * sBias) : nullptr;
    long long coff = (long long)zo * sCo + (long long)zi * sCi;

    // double-buffered: A 128x32 bf16 (8KB), B 64x32 bf16 (4KB) per buffer
    __shared__ __align__(16) short As[2][128 * 32];
    __shared__ __align__(16) short Bs[2][64 * 32];

    int tid = threadIdx.x;
    int m0 = blockIdx.y * 128, n0 = blockIdx.x * 64;

    int l = tid & 63, w = tid >> 6;
    int wm = (w >> 1) * 64, wn = (w & 1) * 32;
    int lr = l & 15, lkB = (l >> 4) * 16;   // byte offset of k-slice within 64B row

    fx4 acc[4][2] = {};

    // staging registers
    bh8 ra0, ra1, rb0;

    int arow = tid >> 2;                 // 0..63 (A rows, +64 for second half)
    int akcB = (tid & 3) * 16;           // byte offset within 64B LDS row
    int bn = tid & 63, bkI = tid >> 6;   // B non-trans mapping

    // row-major [rows, K] loader (A, and B when TRANSB)
    auto loadRowK = [&](const float* P, int r0, int r, int kk, int Rows, int ld) -> bh8 {
        bh8 s;
        if ((r0 + r) < Rows && kk + 8 <= K) {
            const float4* p = reinterpret_cast<const float4*>(P + (long long)(r0 + r) * ld + kk);
            float4 a = p[0], b = p[1];
            s[0] = dk_f2bf(a.x); s[1] = dk_f2bf(a.y); s[2] = dk_f2bf(a.z); s[3] = dk_f2bf(a.w);
            s[4] = dk_f2bf(b.x); s[5] = dk_f2bf(b.y); s[6] = dk_f2bf(b.z); s[7] = dk_f2bf(b.w);
        } else {
#pragma unroll
            for (int j = 0; j < 8; j++) s[j] = 0;
        }
        return s;
    };
    // B non-trans: [K, N], strided along k
    auto loadKN = [&](int n, int kk) -> bh8 {
        bh8 s;
        if ((n0 + n) < N && kk + 8 <= K) {
            const float* p = Bm + (long long)kk * ldb + (n0 + n);
#pragma unroll
            for (int j = 0; j < 8; j++) s[j] = dk_f2bf(p[(long long)j * ldb]);
        } else {
#pragma unroll
            for (int j = 0; j < 8; j++) s[j] = 0;
        }
        return s;
    };

    auto gload = [&](int k0) {
        int kc = k0 + (tid & 3) * 8;
        ra0 = loadRowK(A, m0, arow, kc, M, lda);
        ra1 = loadRowK(A, m0, arow + 64, kc, M, lda);
        if (TRANSB) rb0 = loadRowK(Bm, n0, arow, kc, N, ldb);
        else        rb0 = loadKN(bn, k0 + bkI * 8);
    };
    auto swz = [](int row) { return ((row >> 1) & 3) << 4; };
    auto dswrite = [&](int buf) {
        *(bh8*)((char*)As[buf] + arow * 64 + (akcB ^ swz(arow))) = ra0;
        *(bh8*)((char*)As[buf] + (arow + 64) * 64 + (akcB ^ swz(arow + 64))) = ra1;
        if (TRANSB)
            *(bh8*)((char*)Bs[buf] + arow * 64 + (akcB ^ swz(arow))) = rb0;
        else
            *(bh8*)((char*)Bs[buf] + bn * 64 + ((bkI * 16) ^ swz(bn))) = rb0;
    };

    int NT = (K + 31) / 32;
    // prologue: tile 0 into buf 0 (one exposed latency per block)
    gload(0);
    dswrite(0);
    __syncthreads();
    int cur = 0;
    for (int t = 0; t < NT; ++t) {
        bool more = (t + 1 < NT);
        if (more) gload((t + 1) * 32);   // issue next tile's loads first

        bh8 af[4], bf[2];
#pragma unroll
        for (int mi = 0; mi < 4; mi++) {
            int ra = wm + mi * 16 + lr;
            af[mi] = *(const bh8*)((const char*)As[cur] + ra * 64 + (lkB ^ swz(ra)));
        }
#pragma unroll
        for (int ni = 0; ni < 2; ni++) {
            int rb = wn + ni * 16 + lr;
            bf[ni] = *(const bh8*)((const char*)Bs[cur] + rb * 64 + (lkB ^ swz(rb)));
        }
#pragma unroll
        for (int mi = 0; mi < 4; mi++)
#pragma unroll
            for (int ni = 0; ni < 2; ni++)
                acc[mi][ni] = __builtin_amdgcn_mfma_f32_16x16x32_bf16(af[mi], bf[ni], acc[mi][ni], 0, 0, 0);

        if (more) {
            dswrite(cur ^ 1);     // vmcnt wait largely covered by compute above
            __syncthreads();      // single barrier per K-step
            cur ^= 1;
        }
    }

    // ---- epilogue ----
    const float* R = HAS_RES ? (Rm + coff) : nullptr;
    float* Cc = C + coff;
#pragma unroll
    for (int ni = 0; ni < 2; ni++) {
        int nn = n0 + wn + ni * 16 + lr;
        if (nn >= N) continue;
        float sc = HAS_SCALE ? scale[nn] : 1.0f;
        float bi = biasp ? biasp[nn] : 0.0f;
#pragma unroll
        for (int mi = 0; mi < 4; mi++) {
#pragma unroll
            for (int r = 0; r < 4; r++) {
                int mm = m0 + wm + mi * 16 + (l >> 4) * 4 + r;
                if (mm >= M) continue;
                float v = acc[mi][ni][r];
                if (HAS_SCALE) v *= sc;
                v += bi;
                if (HAS_RES) v += R[(long long)mm * ldc + nn];
                if (ACT == 1) v = fmaxf(v, 0.f);
                if (ACT == 2) v = dk_gelu(v);
                Cc[(long long)mm * ldc + nn] = v;
            }
        }
    }
}

// ---------------- info-exchange MLP (M=8) ----------------
// layer 1: cf1[m,n] = gelu( sum_k cf[m,k] * w1[k,n] + b1[n] ),
//   cf[m,k] = k<768 ? hs[m*CS*CSD + k] : Xc[m*CNN*CD + (k-768)]
__global__ __launch_bounds__(256)
void dk_ie_mlp1(const float* __restrict__ hs, const float* __restrict__ Xc,
                const float* __restrict__ w1, const float* __restrict__ b1,
                float* __restrict__ cf1)
{
    int n = threadIdx.x;
    int m = blockIdx.x;
    if (n >= CIE) return;
    const float* h = hs + (long long)m * CS * CSD;
    const float* x = Xc + (long long)m * CNN * CD;
    float a0 = 0.f, a1 = 0.f, a2 = 0.f, a3 = 0.f;
    int k = 0;
    for (; k + 4 <= CSD; k += 4) {
        a0 += h[k]     * w1[(k)     * CIE + n];
        a1 += h[k + 1] * w1[(k + 1) * CIE + n];
        a2 += h[k + 2] * w1[(k + 2) * CIE + n];
        a3 += h[k + 3] * w1[(k + 3) * CIE + n];
    }
    const float* w1x = w1 + (long long)CSD * CIE;
    for (k = 0; k + 4 <= CD; k += 4) {
        a0 += x[k]     * w1x[(k)     * CIE + n];
        a1 += x[k + 1] * w1x[(k + 1) * CIE + n];
        a2 += x[k + 2] * w1x[(k + 2) * CIE + n];
        a3 += x[k + 3] * w1x[(k + 3) * CIE + n];
    }
    float acc = (a0 + a1) + (a2 + a3) + b1[n];
    cf1[(long long)m * CIE + n] = dk_gelu(acc);
}

// layer 2: cf2[m,n] = sum_k cf1[m,k] * w2[k,n] + b2[n]   (N = 968)
__global__ __launch_bounds__(256)
void dk_ie_mlp2(const float* __restrict__ cf1, const float* __restrict__ w2,
                const float* __restrict__ b2, float* __restrict__ cf2)
{
    int n = blockIdx.x * 256 + threadIdx.x;
    int m = blockIdx.y;
    const int NO = CSD + CD;  // 968
    if (n >= NO) return;
    const float* a = cf1 + (long long)m * CIE;
    float a0 = 0.f, a1 = 0.f, a2 = 0.f, a3 = 0.f;
    for (int k = 0; k + 4 <= CIE; k += 4) {
        a0 += a[k]     * w2[(k)     * NO + n];
        a1 += a[k + 1] * w2[(k + 1) * NO + n];
        a2 += a[k + 2] * w2[(k + 2) * NO + n];
        a3 += a[k + 3] * w2[(k + 3) * NO + n];
    }
    cf2[(long long)m * NO + n] = (a0 + a1) + (a2 + a3) + b2[n];
}

// ---------------- attention softmax (row = one (b,h,q)) ----------------
__global__ __launch_bounds__(256)
void dk_att_softmax(float* __restrict__ att, const float* __restrict__ mask)
{
    int row = blockIdx.x;
    int b = row / (CNH * CS);
    int tid = threadIdx.x;
    float x = att[(long long)row * CS + tid] * 0.125f + mask[b * CS + tid];
    __shared__ float red[256];
    red[tid] = x; __syncthreads();
    for (int s = 128; s; s >>= 1) { if (tid < s) red[tid] = fmaxf(red[tid], red[tid + s]); __syncthreads(); }
    float mx = red[0]; __syncthreads();
    float e = expf(x - mx);
    red[tid] = e; __syncthreads();
    for (int s = 128; s; s >>= 1) { if (tid < s) red[tid] += red[tid + s]; __syncthreads(); }
    float sum = red[0];
    att[(long long)row * CS + tid] = e / sum;
}

// ---------------- layernorm over 768 ----------------
__global__ __launch_bounds__(256)
void dk_ln_row(const float* __restrict__ in, const float* __restrict__ w,
               const float* __restrict__ b, float* __restrict__ out)
{
    int row = blockIdx.x, tid = threadIdx.x;
    const float* ip = in + (long long)row * CSD;
    float xv[3];
    float s = 0.f;
#pragma unroll
    for (int t = 0; t < 3; t++) { xv[t] = ip[tid + t * 256]; s += xv[t]; }
    __shared__ float red[256];
    red[tid] = s; __syncthreads();
    for (int st = 128; st; st >>= 1) { if (tid < st) red[tid] += red[tid + st]; __syncthreads(); }
    float mean = red[0] * (1.f / 768.f); __syncthreads();
    float v = 0.f;
#pragma unroll
    for (int t = 0; t < 3; t++) { float d = xv[t] - mean; v += d * d; }
    red[tid] = v; __syncthreads();
    for (int st = 128; st; st >>= 1) { if (tid < st) red[tid] += red[tid + st]; __syncthreads(); }
    float var = red[0] * (1.f / 768.f);
    float rs = 1.0f / sqrtf(var + 1e-12f);
    float* op = out + (long long)row * CSD;
#pragma unroll
    for (int t = 0; t < 3; t++) {
        int c = tid + t * 256;
        op[c] = (xv[t] - mean) * rs * w[c] + b[c];
    }
}

// ---------------- small utility kernels ----------------
__global__ void dk_copy_f32(const float* __restrict__ a, float* __restrict__ o, long long n)
{
    long long i = (long long)blockIdx.x * 256 + threadIdx.x;
    if (i < n) o[i] = a[i];
}

__global__ void dk_fold_bn(const float* __restrict__ b1, const float* __restrict__ bw,
                           const float* __restrict__ bb, float* __restrict__ sc,
                           float* __restrict__ bs, int n)
{
    int i = blockIdx.x * 256 + threadIdx.x;
    if (i >= n) return;
    float c = 1.0f / sqrtf(1.0f + 1e-5f);
    sc[i] = c * bw[i];
    bs[i] = b1[i] * c * bw[i] + bb[i];
}

__global__ __launch_bounds__(256)
void dk_ee_gather(const float* __restrict__ w1, const float* __restrict__ sc,
                  const float* __restrict__ bs, const int* __restrict__ eidx,
                  const int* __restrict__ etyp, const int* __restrict__ ntyp,
                  float* __restrict__ out)
{
    int e = blockIdx.x, d = threadIdx.x;
    if (d >= CD) return;
    int t0, s, t;
    if (e < CE) { t0 = etyp[e]; s = eidx[e]; t = eidx[CE + e]; }
    else        { t0 = CNET; s = t = e - CE; }
    int h0 = ntyp[s], t1 = ntyp[t];
    float v = w1[t0 * CD + d] + w1[(CNET + 1 + h0) * CD + d] + w1[(CNET + 1 + CNNT + t1) * CD + d];
    v = v * sc[d] + bs[d];
    out[(long long)e * CD + d] = fmaxf(v, 0.f);
}

__global__ void dk_deg_init(float* __restrict__ deg)
{
    int i = blockIdx.x * 256 + threadIdx.x;
    if (i < CN) deg[i] = 1.0f;
}
__global__ void dk_deg_count(const int* __restrict__ eidx, float* __restrict__ deg)
{
    int e = blockIdx.x * 256 + threadIdx.x;
    if (e < CE) atomicAdd(&deg[eidx[e]], 1.0f);
}

__global__ void dk_x2_build(const float* __restrict__ Xc, const float* __restrict__ nfe,
                            float* __restrict__ x2)
{
    int i = blockIdx.x * 256 + threadIdx.x;
    if (i >= CN * 2 * CD) return;
    int n = i / (2 * CD), d = i % (2 * CD);
    x2[i] = (d < CD) ? Xc[(long long)n * CD + d] : nfe[(long long)n * CD + (d - CD)];
}

__global__ __launch_bounds__(256)
void dk_gat_scores(const float* __restrict__ qryN, const float* __restrict__ keyN,
                   const float* __restrict__ keyE, const int* __restrict__ eidx,
                   float* __restrict__ scores, unsigned* __restrict__ smax)
{
    long long id = (long long)blockIdx.x * 256 + threadIdx.x;
    if (id >= (long long)CEN * CHC) return;
    int e = (int)(id >> 2), h = (int)(id & 3);
    int s, t;
    if (e < CE) { s = eidx[e]; t = eidx[CE + e]; } else { s = t = e - CE; }
    const float* qp = qryN + (long long)s * CD + h * CDPH;
    const float* kp = keyN + (long long)t * CD + h * CDPH;
    const float* ke = keyE + (long long)e * CD + h * CDPH;
    float acc = 0.f;
#pragma unroll 10
    for (int d = 0; d < CDPH; d++) acc += qp[d] * (kp[d] + ke[d]);
    acc *= 0.14142135623730950488f;
    scores[id] = acc;
    atomicMax(&smax[s * CHC + h], dk_fenc(acc));
}

__global__ __launch_bounds__(256)
void dk_gat_expsum(const unsigned* __restrict__ smax, const int* __restrict__ eidx,
                   float* __restrict__ scores, float* __restrict__ den)
{
    long long id = (long long)blockIdx.x * 256 + threadIdx.x;
    if (id >= (long long)CEN * CHC) return;
    int e = (int)(id >> 2), h = (int)(id & 3);
    int s;
    if (e < CE) s = eidx[e]; else s = e - CE;
    float ex = expf(scores[id] - dk_fdec(smax[s * CHC + h]));
    scores[id] = ex;
    atomicAdd(&den[s * CHC + h], ex);
}

__global__ __launch_bounds__(256)
void dk_gat_aggr(const float* __restrict__ msgN, const float* __restrict__ msgE,
                 const float* __restrict__ scores, const float* __restrict__ den,
                 const float* __restrict__ deg, const int* __restrict__ eidx,
                 float* __restrict__ aggr)
{
    int e = blockIdx.x, d = threadIdx.x;
    if (d >= CD) return;
    int s, t;
    if (e < CE) { s = eidx[e]; t = eidx[CE + e]; } else { s = t = e - CE; }
    int h = d / CDPH;
    float alpha = scores[(long long)e * CHC + h] / (den[s * CHC + h] + 1e-16f) * deg[s];
    float v = (msgN[(long long)s * CD + d] + msgE[(long long)e * CD + d]) * alpha;
    atomicAdd(&aggr[(long long)t * CD + d], v);
}

__global__ void dk_cf_scatter(const float* __restrict__ cf2, float* __restrict__ hs,
                              float* __restrict__ Xc)
{
    int i = blockIdx.x * 256 + threadIdx.x;
    if (i >= CB * (CSD + CD)) return;
    int b = i / (CSD + CD), c = i % (CSD + CD);
    float v = cf2[i];
    if (c < CSD) hs[(long long)b * CS * CSD + c] = v;
    else         Xc[(long long)b * CNN * CD + (c - CSD)] = v;
}

// ---------------- host-side MFMA GEMM dispatch ----------------
// mode: 0=plain, 1=transb, 2=res, 3=gelu, 4=relu+scale
static void mgemm_go(hipStream_t st, int mode,
                     const float* A, const float* B, const float* bias, long long sBias,
                     const float* scale, const float* R, float* C,
                     int M, int N, int K, int lda, int ldb, int ldc,
                     int batches = 1, int innerB = 1,
                     long long sAo = 0, long long sAi = 0, long long sBo = 0, long long sBi = 0,
                     long long sCo = 0, long long sCi = 0)
{
    dim3 grid((N + 63) / 64, (M + 127) / 128, batches), blk(256);
    switch (mode) {
    case 0: dk_mgemm<false, 0, false, false><<<grid, blk, 0, st>>>(A, B, bias, sBias, scale, R, C, M, N, K, lda, ldb, ldc, innerB, sAo, sAi, sBo, sBi, sCo, sCi); break;
    case 1: dk_mgemm<true,  0, false, false><<<grid, blk, 0, st>>>(A, B, bias, sBias, scale, R, C, M, N, K, lda, ldb, ldc, innerB, sAo, sAi, sBo, sBi, sCo, sCi); break;
    case 2: dk_mgemm<false, 0, false, true ><<<grid, blk, 0, st>>>(A, B, bias, sBias, scale, R, C, M, N, K, lda, ldb, ldc, innerB, sAo, sAi, sBo, sBi, sCo, sCi); break;
    case 3: dk_mgemm<false, 2, false, false><<<grid, blk, 0, st>>>(A, B, bias, sBias, scale, R, C, M, N, K, lda, ldb, ldc, innerB, sAo, sAi, sBo, sBi, sCo, sCi); break;
    case 4: dk_mgemm<false, 1, true,  false><<<grid, blk, 0, st>>>(A, B, bias, sBias, scale, R, C, M, N, K, lda, ldb, ldc, innerB, sAo, sAi, sBo, sBi, sCo, sCi); break;
    }
}

// ---------------- launch ----------------
extern "C" void kernel_launch(void* const* d_in, const int* in_sizes, int n_in,
                              void* d_out, int out_size, void* d_ws, size_t ws_size,
                              hipStream_t stream)
{
    const float* hidden = (const float*)d_in[0];
    const float* amask  = (const float*)d_in[1];
    const float* Xin    = (const float*)d_in[2];
    const float* nfe    = (const float*)d_in[3];
    const float* qkv_w  = (const float*)d_in[4];
    const float* qkv_b  = (const float*)d_in[5];
    const float* aow    = (const float*)d_in[6];
    const float* aob    = (const float*)d_in[7];
    const float* ln1w   = (const float*)d_in[8];
    const float* ln1b   = (const float*)d_in[9];
    const float* f1w    = (const float*)d_in[10];
    const float* f1b    = (const float*)d_in[11];
    const float* f2w    = (const float*)d_in[12];
    const float* f2b    = (const float*)d_in[13];
    const float* ln2w   = (const float*)d_in[14];
    const float* ln2b   = (const float*)d_in[15];
    const float* eew1   = (const float*)d_in[16];
    const float* eeb1   = (const float*)d_in[17];
    const float* eebnw  = (const float*)d_in[18];
    const float* eebnb  = (const float*)d_in[19];
    const float* eew2   = (const float*)d_in[20];
    const float* eeb2   = (const float*)d_in[21];
    const float* gkw    = (const float*)d_in[22];
    const float* gkb    = (const float*)d_in[23];
    const float* gmw    = (const float*)d_in[24];
    const float* gmb    = (const float*)d_in[25];
    const float* gqw    = (const float*)d_in[26];
    const float* gqb    = (const float*)d_in[27];
    const float* mw1    = (const float*)d_in[28];
    const float* mb1    = (const float*)d_in[29];
    const float* mbnw   = (const float*)d_in[30];
    const float* mbnb   = (const float*)d_in[31];
    const float* mw2    = (const float*)d_in[32];
    const float* mb2    = (const float*)d_in[33];
    const float* iew1   = (const float*)d_in[34];
    const float* ieb1   = (const float*)d_in[35];
    const float* iew2   = (const float*)d_in[36];
    const float* ieb2   = (const float*)d_in[37];
    const int*   eidx   = (const int*)d_in[38];
    const int*   etyp   = (const int*)d_in[39];
    const int*   ntyp   = (const int*)d_in[40];

    float* hs    = (float*)d_out;
    float* XcOut = hs + (long long)CB * CS * CSD;

    float* w = (float*)d_ws;
    float* qb   = w + OQ;
    float* kb   = w + OK2;
    float* vb   = w + OV2;
    float* attb = w + OATT;
    float* ctx  = w + OCTX;
    float* tmp  = w + OTMP;
    float* atn  = w + OATN;
    float* inter= w + OINT;
    float* eemb = w + OEE;
    float* keyE = w + OKE;
    float* msgE = w + OME;
    float* x2   = w + OX2;
    float* keyN = w + OKN;
    float* msgN = w + OMN;
    float* qryN = w + OQN;
    float* scrs = w + OSC;
    unsigned* smax = (unsigned*)(w + OSMX);
    float* den  = w + ODEN;
    float* deg  = w + ODEG;
    float* aggr = w + OAGG;
    float* hm   = w + OHM;
    float* Xc   = w + OXC;
    float* cf1  = w + OCF1;
    float* cf2  = w + OCF2;
    float* eeSc = w + OEESC;
    float* eeBs = w + OEEBS;
    float* mlSc = w + OMLSC;
    float* mlBs = w + OMLBS;

    const long long HS_N = (long long)CB * CS * CSD;
    const long long XC_N = (long long)CN * CD;

    // ---- init ----
    dk_copy_f32<<<(unsigned)((HS_N + 255) / 256), 256, 0, stream>>>(hidden, hs, HS_N);
    dk_copy_f32<<<(unsigned)((XC_N + 255) / 256), 256, 0, stream>>>(Xin, Xc, XC_N);
    dk_fold_bn<<<1, 256, 0, stream>>>(eeb1, eebnw, eebnb, eeSc, eeBs, CD);
    dk_fold_bn<<<4, 256, 0, stream>>>(mb1, mbnw, mbnb, mlSc, mlBs, CK * CD);

    // ---- edge embeddings (shared across GAT layers) ----
    dk_ee_gather<<<CEN, 256, 0, stream>>>(eew1, eeSc, eeBs, eidx, etyp, ntyp, keyE);
    mgemm_go(stream, 0, keyE, eew2, eeb2, 0, nullptr, nullptr, eemb,
             CEN, CD, CD, CD, CD, CD);

    // ---- degree ----
    dk_deg_init<<<(CN + 255) / 256, 256, 0, stream>>>(deg);
    dk_deg_count<<<(CE + 255) / 256, 256, 0, stream>>>(eidx, deg);

    const long long sBH = (long long)CS * CSD;
    const long long sAT = (long long)CNH * CS * CS;

    for (int i = 0; i < CL; i++) {
        // qkv: batched z=0,1,2 -> qb,kb,vb (contiguous in ws)
        mgemm_go(stream, 0, hs, qkv_w + (long long)i * 3 * CSD * CSD,
                 qkv_b + (long long)i * 3 * CSD, CSD, nullptr, nullptr, qb,
                 CB * CS, CSD, CSD, CSD, CSD, CSD,
                 3, 1, 0, 0, (long long)CSD * CSD, 0, 1572864LL, 0);
        // scores = q @ k^T (batched over b,h)
        mgemm_go(stream, 1, qb, kb, nullptr, 0, nullptr, nullptr, attb,
                 CS, CS, CDH, CSD, CSD, CS,
                 CB * CNH, CNH, sBH, CDH, sBH, CDH, sAT, (long long)CS * CS);
        dk_att_softmax<<<CB * CNH * CS, 256, 0, stream>>>(attb, amask);
        // ctx = att @ v
        mgemm_go(stream, 0, attb, vb, nullptr, 0, nullptr, nullptr, ctx,
                 CS, CDH, CS, CS, CSD, CSD,
                 CB * CNH, CNH, sAT, (long long)CS * CS, sBH, CDH, sBH, CDH);
        // out proj + residual, then LN1
        mgemm_go(stream, 2, ctx, aow + (long long)i * CSD * CSD,
                 aob + (long long)i * CSD, 0, nullptr, hs, tmp,
                 CB * CS, CSD, CSD, CSD, CSD, CSD);
        dk_ln_row<<<CB * CS, 256, 0, stream>>>(tmp, ln1w + (long long)i * CSD, ln1b + (long long)i * CSD, atn);
        // ffn
        mgemm_go(stream, 3, atn, f1w + (long long)i * CSD * CFF,
                 f1b + (long long)i * CFF, 0, nullptr, nullptr, inter,
                 CB * CS, CFF, CSD, CSD, CFF, CFF);
        mgemm_go(stream, 2, inter, f2w + (long long)i * CFF * CSD,
                 f2b + (long long)i * CSD, 0, nullptr, atn, tmp,
                 CB * CS, CSD, CFF, CFF, CSD, CSD);
        dk_ln_row<<<CB * CS, 256, 0, stream>>>(tmp, ln2w + (long long)i * CSD, ln2b + (long long)i * CSD, hs);

        if (i >= CL - CK) {
            int g = i - (CL - CK);
            dk_x2_build<<<(CN * 2 * CD + 255) / 256, 256, 0, stream>>>(Xc, nfe, x2);
            mgemm_go(stream, 0, x2, gqw + (long long)g * 2 * CD * CD,
                     gqb + (long long)g * CD, 0, nullptr, nullptr, qryN,
                     CN, CD, 2 * CD, 2 * CD, CD, CD);
            mgemm_go(stream, 0, x2, gkw + (long long)g * 3 * CD * CD,
                     gkb + (long long)g * CD, 0, nullptr, nullptr, keyN,
                     CN, CD, 2 * CD, 2 * CD, CD, CD);
            mgemm_go(stream, 0, x2, gmw + (long long)g * 3 * CD * CD,
                     gmb + (long long)g * CD, 0, nullptr, nullptr, msgN,
                     CN, CD, 2 * CD, 2 * CD, CD, CD);
            mgemm_go(stream, 0, eemb,
                     gkw + (long long)g * 3 * CD * CD + (long long)2 * CD * CD,
                     nullptr, 0, nullptr, nullptr, keyE, CEN, CD, CD, CD, CD, CD);
            mgemm_go(stream, 0, eemb,
                     gmw + (long long)g * 3 * CD * CD + (long long)2 * CD * CD,
                     nullptr, 0, nullptr, nullptr, msgE, CEN, CD, CD, CD, CD, CD);
            hipMemsetAsync(smax, 0, CN * CHC * sizeof(unsigned), stream);
            hipMemsetAsync(den, 0, CN * CHC * sizeof(float), stream);
            hipMemsetAsync(aggr, 0, (size_t)CN * CD * sizeof(float), stream);
            dk_gat_scores<<<(CEN * CHC + 255) / 256, 256, 0, stream>>>(qryN, keyN, keyE, eidx, scrs, smax);
            dk_gat_expsum<<<(CEN * CHC + 255) / 256, 256, 0, stream>>>(smax, eidx, scrs, den);
            dk_gat_aggr<<<CEN, 256, 0, stream>>>(msgN, msgE, scrs, den, deg, eidx, aggr);
            mgemm_go(stream, 4, aggr, mw1 + (long long)g * CD * CD,
                     mlBs + (long long)g * CD, 0, mlSc + (long long)g * CD, nullptr, hm,
                     CN, CD, CD, CD, CD, CD);
            mgemm_go(stream, 3, hm, mw2 + (long long)g * CD * CD,
                     mb2 + (long long)g * CD, 0, nullptr, nullptr, Xc,
                     CN, CD, CD, CD, CD, CD);
            // info exchange (M=8 dedicated kernels)
            dk_ie_mlp1<<<CB, 256, 0, stream>>>(hs, Xc, iew1, ieb1, cf1);
            dk_ie_mlp2<<<dim3(4, CB), 256, 0, stream>>>(cf1, iew2, ieb2, cf2);
            dk_cf_scatter<<<(CB * (CSD + CD) + 255) / 256, 256, 0, stream>>>(cf2, hs, Xc);
        }
    }

    dk_copy_f32<<<(unsigned)((XC_N + 255) / 256), 256, 0, stream>>>(Xc, XcOut, XC_N);
}

// Round 5
// 5255.288 us; speedup vs baseline: 4.7237x; 1.2378x over previous
//
#include <hip/hip_runtime.h>
#include <math.h>

// ---------------- problem constants ----------------
namespace {
constexpr int CB = 8, CS = 256, CSD = 768, CL = 12, CNH = 12, CDH = 64, CFF = 3072;
constexpr int CK = 5, CD = 200, CHC = 4, CDPH = 50, CNNT = 4, CNET = 38;
constexpr int CNN = 200, CN = 1600, CE = 50000, CEN = 51600, CIE = 200;
constexpr int CENP = 51712;   // 404*128
constexpr int CNP  = 1664;    // 13*128
constexpr int KP200 = 256, KP400 = 448;

// ---- fp32 workspace offsets (floats) ----
constexpr long long OATT  = 0;                    // att fp32 [96][256][256]
constexpr long long OTMP  = OATT + 6291456;
constexpr long long OATN  = OTMP + 1572864;
constexpr long long OXC   = OATN + 1572864;       // Xc fp32 [1600][200]
constexpr long long OSC   = OXC  + 320000;        // scores [51600*4]
constexpr long long OSMX  = OSC  + 206400;
constexpr long long ODEN  = OSMX + 6400;
constexpr long long ODEG  = ODEN + 6400;
constexpr long long OAGG  = ODEG + 1600;          // aggr fp32 [1600][200]
constexpr long long OQN   = OAGG + 320000;        // qryN fp32 [1600][200]
constexpr long long OKN   = OQN  + 320000;
constexpr long long OMN   = OKN  + 320000;
constexpr long long OCF1  = OMN  + 320000;
constexpr long long OCF2  = OCF1 + 1600;
constexpr long long OEESC = OCF2 + 7744;
constexpr long long OEEBS = OEESC + 200;
constexpr long long OMLSC = OEEBS + 200;
constexpr long long OMLBS = OMLSC + 1000;
constexpr long long OBF   = OMLBS + 1000 + 8;     // bf16 region starts here

// ---- bf16 offsets (ushort units, from OBF) ----
constexpr long long BHSB  = 0;                         // hs_bf [2048][768]
constexpr long long BATNB = BHSB  + 1572864;           // atn_bf
constexpr long long BQKV  = BATNB + 1572864;           // qkv_bf [3][2048][768]
constexpr long long BVT   = BQKV  + 4718592;           // vT [96][128][256]
constexpr long long BATTB = BVT   + 3145728;           // att_bf [96][256][256]
constexpr long long BCTX  = BATTB + 6291456;           // ctx_bf [2048][768]
constexpr long long BINT  = BCTX  + 1572864;           // inter_bf [2048][3072]
constexpr long long BWQKV = BINT  + 6291456;           // qkvT [3][768][768]
constexpr long long BWAO  = BWQKV + 1769472;           // aoT [768][768]
constexpr long long BWF1  = BWAO  + 589824;            // f1T [3072][768]
constexpr long long BWF2  = BWF1  + 2359296;           // f2T [768][3072]
constexpr long long BHEE  = BWF2  + 2359296;           // h_ee [51712][256]
constexpr long long BEEMB = BHEE  + 13238272;          // eemb [51712][256]
constexpr long long BKEYE = BEEMB + 13238272;
constexpr long long BMSGE = BKEYE + 13238272;
constexpr long long BX2   = BMSGE + 13238272;          // x2 [1664][448]
constexpr long long BAGG  = BX2   + 745472;            // aggr_bf [1664][256]
constexpr long long BHM   = BAGG  + 425984;            // hm_bf [1664][256]
constexpr long long BGQ   = BHM   + 425984;            // gqT  [5][256][448]
constexpr long long BGKN  = BGQ   + 573440;            // gkTn [5][256][448]
constexpr long long BGMN  = BGKN  + 573440;            // gmTn [5][256][448]
constexpr long long BGKE  = BGMN  + 573440;            // gkTe [5][256][256]
constexpr long long BGME  = BGKE  + 327680;            // gmTe
constexpr long long BM1   = BGME  + 327680;            // m1T
constexpr long long BM2   = BM1   + 327680;            // m2T
constexpr long long BEW2  = BM2   + 327680;            // eew2T [256][256]
}

typedef unsigned short ushort_t;
typedef __attribute__((ext_vector_type(8))) short bh8;
typedef __attribute__((ext_vector_type(4))) float fx4;

// ---------------- helpers ----------------
__device__ inline unsigned dk_fenc(float f) {
    unsigned u = __float_as_uint(f);
    return (u & 0x80000000u) ? ~u : (u | 0x80000000u);
}
__device__ inline float dk_fdec(unsigned u) {
    return (u & 0x80000000u) ? __uint_as_float(u & 0x7fffffffu) : __uint_as_float(~u);
}
__device__ inline float dk_gelu(float v) {
    return 0.5f * v * (1.0f + erff(v * 0.70710678118654752f));
}
__device__ inline ushort_t dk_f2bf(float f) {
    unsigned u = __float_as_uint(f);
    return (ushort_t)((u + 0x7fffu + ((u >> 16) & 1u)) >> 16);
}
__device__ inline float dk_bf2f(ushort_t h) {
    return __uint_as_float(((unsigned)h) << 16);
}
__device__ __forceinline__ void gl_lds16(const ushort_t* g, ushort_t* l) {
    __builtin_amdgcn_global_load_lds(
        (const __attribute__((address_space(1))) unsigned int*)(g),
        (__attribute__((address_space(3))) unsigned int*)(l), 16, 0, 0);
}

// ---------------- bf16 MFMA GEMM (m97-style), 128x128 tile, BK=64 ----------
// A bf16 [M,K] lda ; B bf16 [N,K] ldb (both K-major, K % 64 == 0 via padding).
// Out: fp32 Cf (cols < N) and/or bf16 Cb (cols < N data, [N,NPAD) zero).
// Optional bias[n] (+ per-z stride), scale[n], fp32 residual R (ld = ldcf).
template<int ACT, bool HAS_SCALE, bool HAS_RES>
__global__ __launch_bounds__(256)
void dk_bgemm(const ushort_t* __restrict__ A, const ushort_t* __restrict__ B,
              const float* __restrict__ bias, long long sBias,
              const float* __restrict__ scale, const float* __restrict__ Rm,
              float* __restrict__ Cf, ushort_t* __restrict__ Cb,
              int M, int N, int NPAD, int K,
              int lda, int ldb, int ldcf, int ldcb,
              int innerB, long long sAo, long long sAi, long long sBo, long long sBi,
              long long sCo, long long sCi)
{
    int z = blockIdx.z;
    int zo = z / innerB, zi = z - zo * innerB;
    A += zo * sAo + zi * sAi;
    B += zo * sBo + zi * sBi;
    long long coff = zo * sCo + zi * sCi;
    const float* biasp = bias ? (bias + (long long)z * sBias) : nullptr;

    __shared__ __align__(16) ushort_t As[128 * 64];
    __shared__ __align__(16) ushort_t Bs[128 * 64];

    int tid = threadIdx.x;
    int l = tid & 63, w = tid >> 6;
    int m0 = blockIdx.y * 128, n0 = blockIdx.x * 128;

    // staging: wave w, instr j covers LDS rows [w*32 + j*8, +8), 128B/row.
    // lane l -> row-in-group l>>3, source chunk (l&7)^(l>>3)  (XOR swizzle,
    // rule #21: permute SOURCE, LDS stays linear for global_load_lds).
    int sj = l >> 3, scb = (l & 7) ^ sj;
    const ushort_t* gA[4]; const ushort_t* gB[4];
    ushort_t* lA[4]; ushort_t* lB[4];
#pragma unroll
    for (int j = 0; j < 4; j++) {
        int row = w * 32 + j * 8 + sj;
        gA[j] = A + (size_t)(m0 + row) * lda + scb * 8;
        gB[j] = B + (size_t)(n0 + row) * ldb + scb * 8;
        lA[j] = As + (w * 4 + j) * 512 + l * 8;
        lB[j] = Bs + (w * 4 + j) * 512 + l * 8;
    }

    int lr = l & 15, hi = l >> 4;
    int wm = (w >> 1) * 64, wn = (w & 1) * 64;
    // fragment byte offsets (read-side swizzle matches source permutation)
    int offA[4][2], offB[4][2];
#pragma unroll
    for (int mi = 0; mi < 4; mi++) {
        int rA = wm + mi * 16 + lr;
        int rB = wn + mi * 16 + lr;
#pragma unroll
        for (int ks = 0; ks < 2; ks++) {
            int g = ks * 4 + hi;
            offA[mi][ks] = rA * 128 + ((g ^ (rA & 7)) << 4);
            offB[mi][ks] = rB * 128 + ((g ^ (rB & 7)) << 4);
        }
    }

    fx4 acc[4][4] = {};
    int NT = K >> 6;
    for (int t = 0; t < NT; ++t) {
        int k0 = t << 6;
        if (t) __syncthreads();
#pragma unroll
        for (int j = 0; j < 4; j++) {
            gl_lds16(gA[j] + k0, lA[j]);
            gl_lds16(gB[j] + k0, lB[j]);
        }
        __syncthreads();   // compiler emits vmcnt(0) drain + barrier
#pragma unroll
        for (int ks = 0; ks < 2; ks++) {
            bh8 af[4], bf[4];
#pragma unroll
            for (int mi = 0; mi < 4; mi++)
                af[mi] = *(const bh8*)((const char*)As + offA[mi][ks]);
#pragma unroll
            for (int ni = 0; ni < 4; ni++)
                bf[ni] = *(const bh8*)((const char*)Bs + offB[ni][ks]);
#pragma unroll
            for (int mi = 0; mi < 4; mi++)
#pragma unroll
                for (int ni = 0; ni < 4; ni++)
                    acc[mi][ni] = __builtin_amdgcn_mfma_f32_16x16x32_bf16(af[mi], bf[ni], acc[mi][ni], 0, 0, 0);
        }
    }

    // ---- epilogue ----
    const float* R = HAS_RES ? (Rm + coff) : nullptr;
    float* cf = Cf ? (Cf + coff) : nullptr;
    ushort_t* cb = Cb ? (Cb + coff) : nullptr;
#pragma unroll
    for (int ni = 0; ni < 4; ni++) {
        int nn = n0 + wn + ni * 16 + lr;
        if (nn >= NPAD) continue;
        bool vn = nn < N;
        float sc = (HAS_SCALE && vn) ? scale[nn] : 1.0f;
        float bi = (biasp && vn) ? biasp[nn] : 0.0f;
#pragma unroll
        for (int mi = 0; mi < 4; mi++) {
#pragma unroll
            for (int r = 0; r < 4; r++) {
                int mm = m0 + wm + mi * 16 + hi * 4 + r;
                if (mm >= M) continue;
                float v = 0.0f;
                if (vn) {
                    v = acc[mi][ni][r];
                    if (HAS_SCALE) v *= sc;
                    v += bi;
                    if (HAS_RES) v += R[(size_t)mm * ldcf + nn];
                    if (ACT == 1) v = fmaxf(v, 0.f);
                    if (ACT == 2) v = dk_gelu(v);
                }
                if (cf && vn) cf[(size_t)mm * ldcf + nn] = v;
                if (cb) cb[(size_t)mm * ldcb + nn] = dk_f2bf(v);
            }
        }
    }
}

// ---------------- transpose-cast: fp32 [K][N] -> bf16 [Np][Kp], zero-pad ----
__global__ __launch_bounds__(256)
void dk_tcast(const float* __restrict__ in, ushort_t* __restrict__ out,
              int K, int N, int ldin, int Np, int Kp,
              long long sIn, long long sOut)
{
    in  += (long long)blockIdx.z * sIn;
    out += (long long)blockIdx.z * sOut;
    int kb = blockIdx.x * 64, nb = blockIdx.y * 64;
    __shared__ float T[64][65];
    int t = threadIdx.x;
    int x = t & 63;
#pragma unroll
    for (int i = 0; i < 16; ++i) {
        int y = (t >> 6) * 16 + i;
        float v = (kb + y < K && nb + x < N) ? in[(size_t)(kb + y) * ldin + nb + x] : 0.f;
        T[y][x] = v;
    }
    __syncthreads();
#pragma unroll
    for (int i = 0; i < 16; ++i) {
        int y = (t >> 6) * 16 + i;
        int n = nb + y, k = kb + x;
        if (n < Np && k < Kp) out[(size_t)n * Kp + k] = dk_f2bf(T[x][y]);
    }
}

// ---------------- v [2048][768] bf16 -> vT [96][128][256] (rows 64..127 unused)
__global__ __launch_bounds__(256)
void dk_vtrans(const ushort_t* __restrict__ v, ushort_t* __restrict__ vT)
{
    int sb = blockIdx.x;            // s-block 0..3
    int z  = blockIdx.y;            // b*12+h
    int b = z / CNH, h = z - b * CNH;
    __shared__ ushort_t T[64][65];
    int t = threadIdx.x;
    int d = t & 63;
#pragma unroll
    for (int i = 0; i < 16; ++i) {
        int si = (t >> 6) * 16 + i;
        T[si][d] = v[(size_t)(b * 256 + sb * 64 + si) * 768 + h * 64 + d];
    }
    __syncthreads();
    int sjj = t & 63;
#pragma unroll
    for (int i = 0; i < 16; ++i) {
        int dd = (t >> 6) * 16 + i;
        vT[(size_t)z * 32768 + (size_t)dd * 256 + sb * 64 + sjj] = T[sjj][dd];
    }
}

// ---------------- attention softmax: fp32 att -> bf16 att_bf --------------
__global__ __launch_bounds__(256)
void dk_att_softmax(const float* __restrict__ att, const float* __restrict__ mask,
                    ushort_t* __restrict__ attb)
{
    int row = blockIdx.x;
    int b = row / (CNH * CS);
    int tid = threadIdx.x;
    float x = att[(long long)row * CS + tid] * 0.125f + mask[b * CS + tid];
    __shared__ float red[256];
    red[tid] = x; __syncthreads();
    for (int s = 128; s; s >>= 1) { if (tid < s) red[tid] = fmaxf(red[tid], red[tid + s]); __syncthreads(); }
    float mx = red[0]; __syncthreads();
    float e = expf(x - mx);
    red[tid] = e; __syncthreads();
    for (int s = 128; s; s >>= 1) { if (tid < s) red[tid] += red[tid + s]; __syncthreads(); }
    float sum = red[0];
    attb[(long long)row * CS + tid] = dk_f2bf(e / sum);
}

// ---------------- layernorm over 768: fp32 in -> fp32 + bf16 out ---------
__global__ __launch_bounds__(256)
void dk_ln_row(const float* __restrict__ in, const float* __restrict__ w,
               const float* __restrict__ b, float* __restrict__ out,
               ushort_t* __restrict__ outb)
{
    int row = blockIdx.x, tid = threadIdx.x;
    const float* ip = in + (long long)row * CSD;
    float xv[3];
    float s = 0.f;
#pragma unroll
    for (int t = 0; t < 3; t++) { xv[t] = ip[tid + t * 256]; s += xv[t]; }
    __shared__ float red[256];
    red[tid] = s; __syncthreads();
    for (int st = 128; st; st >>= 1) { if (tid < st) red[tid] += red[tid + st]; __syncthreads(); }
    float mean = red[0] * (1.f / 768.f); __syncthreads();
    float v = 0.f;
#pragma unroll
    for (int t = 0; t < 3; t++) { float d = xv[t] - mean; v += d * d; }
    red[tid] = v; __syncthreads();
    for (int st = 128; st; st >>= 1) { if (tid < st) red[tid] += red[tid + st]; __syncthreads(); }
    float var = red[0] * (1.f / 768.f);
    float rs = 1.0f / sqrtf(var + 1e-12f);
    float* op = out + (long long)row * CSD;
    ushort_t* ob = outb + (long long)row * CSD;
#pragma unroll
    for (int t = 0; t < 3; t++) {
        int c = tid + t * 256;
        float y = (xv[t] - mean) * rs * w[c] + b[c];
        op[c] = y;
        ob[c] = dk_f2bf(y);
    }
}

// ---------------- small utility kernels ----------------
__global__ void dk_copy_f32(const float* __restrict__ a, float* __restrict__ o, long long n)
{
    long long i = (long long)blockIdx.x * 256 + threadIdx.x;
    if (i < n) o[i] = a[i];
}

__global__ void dk_init_hs(const float* __restrict__ in, float* __restrict__ out,
                           ushort_t* __restrict__ outb, long long n)
{
    long long i = (long long)blockIdx.x * 256 + threadIdx.x;
    if (i < n) { float v = in[i]; out[i] = v; outb[i] = dk_f2bf(v); }
}

__global__ void dk_fold_bn(const float* __restrict__ b1, const float* __restrict__ bw,
                           const float* __restrict__ bb, float* __restrict__ sc,
                           float* __restrict__ bs, int n)
{
    int i = blockIdx.x * 256 + threadIdx.x;
    if (i >= n) return;
    float c = 1.0f / sqrtf(1.0f + 1e-5f);
    sc[i] = c * bw[i];
    bs[i] = b1[i] * c * bw[i] + bb[i];
}

// edge-encoder layer 1 -> bf16 [51712][256] (cols >= 200 zero)
__global__ __launch_bounds__(256)
void dk_ee_gather(const float* __restrict__ w1, const float* __restrict__ sc,
                  const float* __restrict__ bs, const int* __restrict__ eidx,
                  const int* __restrict__ etyp, const int* __restrict__ ntyp,
                  ushort_t* __restrict__ out)
{
    int e = blockIdx.x, d = threadIdx.x;
    float v = 0.f;
    if (d < CD) {
        int t0, s, t;
        if (e < CE) { t0 = etyp[e]; s = eidx[e]; t = eidx[CE + e]; }
        else        { t0 = CNET; s = t = e - CE; }
        int h0 = ntyp[s], t1 = ntyp[t];
        v = w1[t0 * CD + d] + w1[(CNET + 1 + h0) * CD + d] + w1[(CNET + 1 + CNNT + t1) * CD + d];
        v = fmaxf(v * sc[d] + bs[d], 0.f);
    }
    out[(size_t)e * KP200 + d] = dk_f2bf(v);
}

__global__ void dk_deg_init(float* __restrict__ deg)
{
    int i = blockIdx.x * 256 + threadIdx.x;
    if (i < CN) deg[i] = 1.0f;
}
__global__ void dk_deg_count(const int* __restrict__ eidx, float* __restrict__ deg)
{
    int e = blockIdx.x * 256 + threadIdx.x;
    if (e < CE) atomicAdd(&deg[eidx[e]], 1.0f);
}

// x2 bf16 [1664][448]: cols 0..199 Xc, 200..399 nfe, 400..447 zero
__global__ void dk_x2_build(const float* __restrict__ Xc, const float* __restrict__ nfe,
                            ushort_t* __restrict__ x2)
{
    int i = blockIdx.x * 256 + threadIdx.x;
    if (i >= CN * KP400) return;
    int n = i / KP400, d = i - n * KP400;
    float v = (d < CD) ? Xc[(size_t)n * CD + d]
            : (d < 2 * CD ? nfe[(size_t)n * CD + (d - CD)] : 0.f);
    x2[i] = dk_f2bf(v);
}

// aggr fp32 [1600][200] -> bf16 [1664][256] (cols >= 200 zero)
__global__ void dk_cast_pad(const float* __restrict__ in, ushort_t* __restrict__ out)
{
    int i = blockIdx.x * 256 + threadIdx.x;
    if (i >= CN * KP200) return;
    int r = i / KP200, c = i - r * KP200;
    out[i] = (c < CD) ? dk_f2bf(in[(size_t)r * CD + c]) : 0;
}

__global__ __launch_bounds__(256)
void dk_gat_scores(const float* __restrict__ qryN, const float* __restrict__ keyN,
                   const ushort_t* __restrict__ keyE, const int* __restrict__ eidx,
                   float* __restrict__ scores, unsigned* __restrict__ smax)
{
    long long id = (long long)blockIdx.x * 256 + threadIdx.x;
    if (id >= (long long)CEN * CHC) return;
    int e = (int)(id >> 2), h = (int)(id & 3);
    int s, t;
    if (e < CE) { s = eidx[e]; t = eidx[CE + e]; } else { s = t = e - CE; }
    const float* qp = qryN + (long long)s * CD + h * CDPH;
    const float* kp = keyN + (long long)t * CD + h * CDPH;
    const ushort_t* ke = keyE + (size_t)e * KP200 + h * CDPH;
    float acc = 0.f;
#pragma unroll 10
    for (int d = 0; d < CDPH; d++) acc += qp[d] * (kp[d] + dk_bf2f(ke[d]));
    acc *= 0.14142135623730950488f;
    scores[id] = acc;
    atomicMax(&smax[s * CHC + h], dk_fenc(acc));
}

__global__ __launch_bounds__(256)
void dk_gat_expsum(const unsigned* __restrict__ smax, const int* __restrict__ eidx,
                   float* __restrict__ scores, float* __restrict__ den)
{
    long long id = (long long)blockIdx.x * 256 + threadIdx.x;
    if (id >= (long long)CEN * CHC) return;
    int e = (int)(id >> 2), h = (int)(id & 3);
    int s;
    if (e < CE) s = eidx[e]; else s = e - CE;
    float ex = expf(scores[id] - dk_fdec(smax[s * CHC + h]));
    scores[id] = ex;
    atomicAdd(&den[s * CHC + h], ex);
}

__global__ __launch_bounds__(256)
void dk_gat_aggr(const float* __restrict__ msgN, const ushort_t* __restrict__ msgE,
                 const float* __restrict__ scores, const float* __restrict__ den,
                 const float* __restrict__ deg, const int* __restrict__ eidx,
                 float* __restrict__ aggr)
{
    int e = blockIdx.x, d = threadIdx.x;
    if (d >= CD) return;
    int s, t;
    if (e < CE) { s = eidx[e]; t = eidx[CE + e]; } else { s = t = e - CE; }
    int h = d / CDPH;
    float alpha = scores[(long long)e * CHC + h] / (den[s * CHC + h] + 1e-16f) * deg[s];
    float v = (msgN[(long long)s * CD + d] + dk_bf2f(msgE[(size_t)e * KP200 + d])) * alpha;
    atomicAdd(&aggr[(long long)t * CD + d], v);
}

// ---------------- info-exchange MLP (M=8) ----------------
__global__ __launch_bounds__(256)
void dk_ie_mlp1(const float* __restrict__ hs, const float* __restrict__ Xc,
                const float* __restrict__ w1, const float* __restrict__ b1,
                float* __restrict__ cf1)
{
    int n = threadIdx.x;
    int m = blockIdx.x;
    if (n >= CIE) return;
    const float* h = hs + (long long)m * CS * CSD;
    const float* x = Xc + (long long)m * CNN * CD;
    float a0 = 0.f, a1 = 0.f, a2 = 0.f, a3 = 0.f;
    int k = 0;
    for (; k + 4 <= CSD; k += 4) {
        a0 += h[k]     * w1[(k)     * CIE + n];
        a1 += h[k + 1] * w1[(k + 1) * CIE + n];
        a2 += h[k + 2] * w1[(k + 2) * CIE + n];
        a3 += h[k + 3] * w1[(k + 3) * CIE + n];
    }
    const float* w1x = w1 + (long long)CSD * CIE;
    for (k = 0; k + 4 <= CD; k += 4) {
        a0 += x[k]     * w1x[(k)     * CIE + n];
        a1 += x[k + 1] * w1x[(k + 1) * CIE + n];
        a2 += x[k + 2] * w1x[(k + 2) * CIE + n];
        a3 += x[k + 3] * w1x[(k + 3) * CIE + n];
    }
    float acc = (a0 + a1) + (a2 + a3) + b1[n];
    cf1[(long long)m * CIE + n] = dk_gelu(acc);
}

__global__ __launch_bounds__(256)
void dk_ie_mlp2(const float* __restrict__ cf1, const float* __restrict__ w2,
                const float* __restrict__ b2, float* __restrict__ cf2)
{
    int n = blockIdx.x * 256 + threadIdx.x;
    int m = blockIdx.y;
    const int NO = CSD + CD;
    if (n >= NO) return;
    const float* a = cf1 + (long long)m * CIE;
    float a0 = 0.f, a1 = 0.f, a2 = 0.f, a3 = 0.f;
    for (int k = 0; k + 4 <= CIE; k += 4) {
        a0 += a[k]     * w2[(k)     * NO + n];
        a1 += a[k + 1] * w2[(k + 1) * NO + n];
        a2 += a[k + 2] * w2[(k + 2) * NO + n];
        a3 += a[k + 3] * w2[(k + 3) * NO + n];
    }
    cf2[(long long)m * NO + n] = (a0 + a1) + (a2 + a3) + b2[n];
}

__global__ void dk_cf_scatter(const float* __restrict__ cf2, float* __restrict__ hs,
                              ushort_t* __restrict__ hsb, float* __restrict__ Xc)
{
    int i = blockIdx.x * 256 + threadIdx.x;
    if (i >= CB * (CSD + CD)) return;
    int b = i / (CSD + CD), c = i - b * (CSD + CD);
    float v = cf2[i];
    if (c < CSD) {
        hs[(long long)b * CS * CSD + c] = v;
        hsb[(long long)b * CS * CSD + c] = dk_f2bf(v);
    } else {
        Xc[(long long)b * CNN * CD + (c - CSD)] = v;
    }
}

// ---------------- host-side dispatch ----------------
// mode: 0 plain, 1 +fp32 residual, 2 gelu, 3 relu+scale
static void bgemm(hipStream_t st, int mode,
                  const ushort_t* A, const ushort_t* B,
                  const float* bias, long long sBias, const float* scale, const float* R,
                  float* Cf, ushort_t* Cb,
                  int M, int N, int NPAD, int K, int lda, int ldb, int ldcf, int ldcb,
                  int nz = 1, int innerB = 1,
                  long long sAo = 0, long long sAi = 0, long long sBo = 0, long long sBi = 0,
                  long long sCo = 0, long long sCi = 0)
{
    dim3 grid((NPAD + 127) / 128, (M + 127) / 128, nz), blk(256);
    switch (mode) {
    case 0: dk_bgemm<0, false, false><<<grid, blk, 0, st>>>(A, B, bias, sBias, scale, R, Cf, Cb, M, N, NPAD, K, lda, ldb, ldcf, ldcb, innerB, sAo, sAi, sBo, sBi, sCo, sCi); break;
    case 1: dk_bgemm<0, false, true ><<<grid, blk, 0, st>>>(A, B, bias, sBias, scale, R, Cf, Cb, M, N, NPAD, K, lda, ldb, ldcf, ldcb, innerB, sAo, sAi, sBo, sBi, sCo, sCi); break;
    case 2: dk_bgemm<2, false, false><<<grid, blk, 0, st>>>(A, B, bias, sBias, scale, R, Cf, Cb, M, N, NPAD, K, lda, ldb, ldcf, ldcb, innerB, sAo, sAi, sBo, sBi, sCo, sCi); break;
    case 3: dk_bgemm<1, true,  false><<<grid, blk, 0, st>>>(A, B, bias, sBias, scale, R, Cf, Cb, M, N, NPAD, K, lda, ldb, ldcf, ldcb, innerB, sAo, sAi, sBo, sBi, sCo, sCi); break;
    }
}

static void tcast(hipStream_t st, const float* in, ushort_t* out, int K, int N, int ldin,
                  int Np, int Kp, int nz = 1, long long sIn = 0, long long sOut = 0)
{
    dim3 grid((Kp + 63) / 64, (Np + 63) / 64, nz), blk(256);
    dk_tcast<<<grid, blk, 0, st>>>(in, out, K, N, ldin, Np, Kp, sIn, sOut);
}

// ---------------- launch ----------------
extern "C" void kernel_launch(void* const* d_in, const int* in_sizes, int n_in,
                              void* d_out, int out_size, void* d_ws, size_t ws_size,
                              hipStream_t stream)
{
    const float* hidden = (const float*)d_in[0];
    const float* amask  = (const float*)d_in[1];
    const float* Xin    = (const float*)d_in[2];
    const float* nfe    = (const float*)d_in[3];
    const float* qkv_w  = (const float*)d_in[4];
    const float* qkv_b  = (const float*)d_in[5];
    const float* aow    = (const float*)d_in[6];
    const float* aob    = (const float*)d_in[7];
    const float* ln1w   = (const float*)d_in[8];
    const float* ln1b   = (const float*)d_in[9];
    const float* f1w    = (const float*)d_in[10];
    const float* f1b    = (const float*)d_in[11];
    const float* f2w    = (const float*)d_in[12];
    const float* f2b    = (const float*)d_in[13];
    const float* ln2w   = (const float*)d_in[14];
    const float* ln2b   = (const float*)d_in[15];
    const float* eew1   = (const float*)d_in[16];
    const float* eeb1   = (const float*)d_in[17];
    const float* eebnw  = (const float*)d_in[18];
    const float* eebnb  = (const float*)d_in[19];
    const float* eew2   = (const float*)d_in[20];
    const float* eeb2   = (const float*)d_in[21];
    const float* gkw    = (const float*)d_in[22];
    const float* gkb    = (const float*)d_in[23];
    const float* gmw    = (const float*)d_in[24];
    const float* gmb    = (const float*)d_in[25];
    const float* gqw    = (const float*)d_in[26];
    const float* gqb    = (const float*)d_in[27];
    const float* mw1    = (const float*)d_in[28];
    const float* mb1    = (const float*)d_in[29];
    const float* mbnw   = (const float*)d_in[30];
    const float* mbnb   = (const float*)d_in[31];
    const float* mw2    = (const float*)d_in[32];
    const float* mb2    = (const float*)d_in[33];
    const float* iew1   = (const float*)d_in[34];
    const float* ieb1   = (const float*)d_in[35];
    const float* iew2   = (const float*)d_in[36];
    const float* ieb2   = (const float*)d_in[37];
    const int*   eidx   = (const int*)d_in[38];
    const int*   etyp   = (const int*)d_in[39];
    const int*   ntyp   = (const int*)d_in[40];

    float* hs    = (float*)d_out;
    float* XcOut = hs + (long long)CB * CS * CSD;

    float* w = (float*)d_ws;
    float* attf = w + OATT;
    float* tmp  = w + OTMP;
    float* atn  = w + OATN;
    float* Xc   = w + OXC;
    float* scrs = w + OSC;
    unsigned* smax = (unsigned*)(w + OSMX);
    float* den  = w + ODEN;
    float* deg  = w + ODEG;
    float* aggr = w + OAGG;
    float* qryN = w + OQN;
    float* keyN = w + OKN;
    float* msgN = w + OMN;
    float* cf1  = w + OCF1;
    float* cf2  = w + OCF2;
    float* eeSc = w + OEESC;
    float* eeBs = w + OEEBS;
    float* mlSc = w + OMLSC;
    float* mlBs = w + OMLBS;

    ushort_t* bb = (ushort_t*)(w + OBF);
    ushort_t* hs_b   = bb + BHSB;
    ushort_t* atn_b  = bb + BATNB;
    ushort_t* qkv_bf = bb + BQKV;       // q = +0, k = +1572864, v = +3145728
    ushort_t* vT     = bb + BVT;
    ushort_t* att_b  = bb + BATTB;
    ushort_t* ctx_b  = bb + BCTX;
    ushort_t* int_b  = bb + BINT;
    ushort_t* wqkvT  = bb + BWQKV;
    ushort_t* waoT   = bb + BWAO;
    ushort_t* wf1T   = bb + BWF1;
    ushort_t* wf2T   = bb + BWF2;
    ushort_t* hee    = bb + BHEE;
    ushort_t* eemb   = bb + BEEMB;
    ushort_t* keyE   = bb + BKEYE;
    ushort_t* msgE   = bb + BMSGE;
    ushort_t* x2_b   = bb + BX2;
    ushort_t* aggr_b = bb + BAGG;
    ushort_t* hm_b   = bb + BHM;
    ushort_t* gqT    = bb + BGQ;
    ushort_t* gkTn   = bb + BGKN;
    ushort_t* gmTn   = bb + BGMN;
    ushort_t* gkTe   = bb + BGKE;
    ushort_t* gmTe   = bb + BGME;
    ushort_t* m1T    = bb + BM1;
    ushort_t* m2T    = bb + BM2;
    ushort_t* eew2T  = bb + BEW2;

    const long long HS_N = (long long)CB * CS * CSD;
    const long long XC_N = (long long)CN * CD;

    // ---- init ----
    dk_init_hs<<<(unsigned)((HS_N + 255) / 256), 256, 0, stream>>>(hidden, hs, hs_b, HS_N);
    dk_copy_f32<<<(unsigned)((XC_N + 255) / 256), 256, 0, stream>>>(Xin, Xc, XC_N);
    dk_fold_bn<<<1, 256, 0, stream>>>(eeb1, eebnw, eebnb, eeSc, eeBs, CD);
    dk_fold_bn<<<4, 256, 0, stream>>>(mb1, mbnw, mbnb, mlSc, mlBs, CK * CD);

    // ---- GAT weight conversions (once) ----
    tcast(stream, eew2, eew2T, CD, CD, CD, KP200, KP200);
    tcast(stream, gqw, gqT, 2 * CD, CD, CD, KP200, KP400, CK, 2LL * CD * CD, 114688LL);
    tcast(stream, gkw, gkTn, 2 * CD, CD, CD, KP200, KP400, CK, 3LL * CD * CD, 114688LL);
    tcast(stream, gmw, gmTn, 2 * CD, CD, CD, KP200, KP400, CK, 3LL * CD * CD, 114688LL);
    tcast(stream, gkw + 2 * CD * CD, gkTe, CD, CD, CD, KP200, KP200, CK, 3LL * CD * CD, 65536LL);
    tcast(stream, gmw + 2 * CD * CD, gmTe, CD, CD, CD, KP200, KP200, CK, 3LL * CD * CD, 65536LL);
    tcast(stream, mw1, m1T, CD, CD, CD, KP200, KP200, CK, (long long)CD * CD, 65536LL);
    tcast(stream, mw2, m2T, CD, CD, CD, KP200, KP200, CK, (long long)CD * CD, 65536LL);

    // ---- edge embeddings (shared across GAT layers) ----
    dk_ee_gather<<<CEN, 256, 0, stream>>>(eew1, eeSc, eeBs, eidx, etyp, ntyp, hee);
    bgemm(stream, 0, hee, eew2T, eeb2, 0, nullptr, nullptr, nullptr, eemb,
          CEN, CD, KP200, KP200, KP200, KP200, 0, KP200);

    // ---- degree ----
    dk_deg_init<<<(CN + 255) / 256, 256, 0, stream>>>(deg);
    dk_deg_count<<<(CE + 255) / 256, 256, 0, stream>>>(eidx, deg);

    for (int i = 0; i < CL; i++) {
        // per-layer weight conversion
        tcast(stream, qkv_w + (long long)i * 3 * CSD * CSD, wqkvT, CSD, CSD, CSD, CSD, CSD,
              3, (long long)CSD * CSD, (long long)CSD * CSD);
        tcast(stream, aow + (long long)i * CSD * CSD, waoT, CSD, CSD, CSD, CSD, CSD);
        tcast(stream, f1w + (long long)i * CSD * CFF, wf1T, CSD, CFF, CFF, CFF, CSD);
        tcast(stream, f2w + (long long)i * CFF * CSD, wf2T, CFF, CSD, CSD, CSD, CFF);

        // qkv (z = 0,1,2)
        bgemm(stream, 0, hs_b, wqkvT, qkv_b + (long long)i * 3 * CSD, CSD, nullptr, nullptr,
              nullptr, qkv_bf, 2048, CSD, CSD, CSD, CSD, CSD, 0, CSD,
              3, 1, 0, 0, (long long)CSD * CSD, 0, (long long)2048 * CSD, 0);
        // v -> vT
        dk_vtrans<<<dim3(4, 96), 256, 0, stream>>>(qkv_bf + 2LL * 2048 * CSD, vT);
        // QK^T -> att fp32
        bgemm(stream, 0, qkv_bf, qkv_bf + 1572864, nullptr, 0, nullptr, nullptr,
              attf, nullptr, CS, CS, CS, 64, CSD, CSD, CS, 0,
              96, CNH, (long long)CS * CSD, 64, (long long)CS * CSD, 64,
              (long long)CNH * CS * CS, (long long)CS * CS);
        dk_att_softmax<<<96 * CS, 256, 0, stream>>>(attf, amask, att_b);
        // PV -> ctx bf16
        bgemm(stream, 0, att_b, vT, nullptr, 0, nullptr, nullptr,
              nullptr, ctx_b, CS, CDH, CDH, CS, CS, CS, 0, CSD,
              96, CNH, (long long)CNH * CS * CS, (long long)CS * CS,
              (long long)CNH * 32768, 32768, (long long)CS * CSD, CDH);
        // out proj + residual -> tmp, then LN1 -> atn (+bf16)
        bgemm(stream, 1, ctx_b, waoT, aob + (long long)i * CSD, 0, nullptr, hs,
              tmp, nullptr, 2048, CSD, CSD, CSD, CSD, CSD, CSD, 0);
        dk_ln_row<<<2048, 256, 0, stream>>>(tmp, ln1w + (long long)i * CSD, ln1b + (long long)i * CSD, atn, atn_b);
        // ffn1 (gelu) -> inter bf16
        bgemm(stream, 2, atn_b, wf1T, f1b + (long long)i * CFF, 0, nullptr, nullptr,
              nullptr, int_b, 2048, CFF, CFF, CSD, CSD, CSD, 0, CFF);
        // ffn2 + residual(atn) -> tmp, LN2 -> hs (+bf16)
        bgemm(stream, 1, int_b, wf2T, f2b + (long long)i * CSD, 0, nullptr, atn,
              tmp, nullptr, 2048, CSD, CSD, CFF, CFF, CFF, CSD, 0);
        dk_ln_row<<<2048, 256, 0, stream>>>(tmp, ln2w + (long long)i * CSD, ln2b + (long long)i * CSD, hs, hs_b);

        if (i >= CL - CK) {
            int g = i - (CL - CK);
            dk_x2_build<<<(CN * KP400 + 255) / 256, 256, 0, stream>>>(Xc, nfe, x2_b);
            // node projections (fp32 out)
            bgemm(stream, 0, x2_b, gqT + (long long)g * 114688, gqb + (long long)g * CD, 0,
                  nullptr, nullptr, qryN, nullptr, CN, CD, CD, KP400, KP400, KP400, CD, 0);
            bgemm(stream, 0, x2_b, gkTn + (long long)g * 114688, gkb + (long long)g * CD, 0,
                  nullptr, nullptr, keyN, nullptr, CN, CD, CD, KP400, KP400, KP400, CD, 0);
            bgemm(stream, 0, x2_b, gmTn + (long long)g * 114688, gmb + (long long)g * CD, 0,
                  nullptr, nullptr, msgN, nullptr, CN, CD, CD, KP400, KP400, KP400, CD, 0);
            // edge projections (bf16 out)
            bgemm(stream, 0, eemb, gkTe + (long long)g * 65536, nullptr, 0, nullptr, nullptr,
                  nullptr, keyE, CEN, CD, KP200, KP200, KP200, KP200, 0, KP200);
            bgemm(stream, 0, eemb, gmTe + (long long)g * 65536, nullptr, 0, nullptr, nullptr,
                  nullptr, msgE, CEN, CD, KP200, KP200, KP200, KP200, 0, KP200);
            // segment softmax + aggregate
            hipMemsetAsync(smax, 0, CN * CHC * sizeof(unsigned), stream);
            hipMemsetAsync(den, 0, CN * CHC * sizeof(float), stream);
            hipMemsetAsync(aggr, 0, (size_t)CN * CD * sizeof(float), stream);
            dk_gat_scores<<<(CEN * CHC + 255) / 256, 256, 0, stream>>>(qryN, keyN, keyE, eidx, scrs, smax);
            dk_gat_expsum<<<(CEN * CHC + 255) / 256, 256, 0, stream>>>(smax, eidx, scrs, den);
            dk_gat_aggr<<<CEN, 256, 0, stream>>>(msgN, msgE, scrs, den, deg, eidx, aggr);
            dk_cast_pad<<<(CN * KP200 + 255) / 256, 256, 0, stream>>>(aggr, aggr_b);
            // mlp
            bgemm(stream, 3, aggr_b, m1T + (long long)g * 65536, mlBs + (long long)g * CD, 0,
                  mlSc + (long long)g * CD, nullptr, nullptr, hm_b,
                  CN, CD, KP200, KP200, KP200, KP200, 0, KP200);
            bgemm(stream, 2, hm_b, m2T + (long long)g * 65536, mb2 + (long long)g * CD, 0,
                  nullptr, nullptr, Xc, nullptr, CN, CD, CD, KP200, KP200, KP200, CD, 0);
            // info exchange
            dk_ie_mlp1<<<CB, 256, 0, stream>>>(hs, Xc, iew1, ieb1, cf1);
            dk_ie_mlp2<<<dim3(4, CB), 256, 0, stream>>>(cf1, iew2, ieb2, cf2);
            dk_cf_scatter<<<(CB * (CSD + CD) + 255) / 256, 256, 0, stream>>>(cf2, hs, hs_b, Xc);
        }
    }

    dk_copy_f32<<<(unsigned)((XC_N + 255) / 256), 256, 0, stream>>>(Xc, XcOut, XC_N);
}